// Round 14
// baseline (1432.613 us; speedup 1.0000x reference)
//
#include <hip/hip_runtime.h>

#define TT 1024
#define HH 128

typedef unsigned int u32;
typedef unsigned short u16;
typedef _Float16 f16;
typedef f16 f16x2 __attribute__((ext_vector_type(2)));
typedef f16 f16x8 __attribute__((ext_vector_type(8)));
typedef float f32x4 __attribute__((ext_vector_type(4)));
typedef u32 u32x4 __attribute__((ext_vector_type(4)));
typedef u32 u32x2 __attribute__((ext_vector_type(2)));

#define MFMA16(A, B, C) __builtin_amdgcn_mfma_f32_16x16x32_f16((A), (B), (C), 0, 0, 0)
#define K2L2E 2.8853900817779268f   /* 2*log2(e) */

__device__ __forceinline__ float ex2(float x) {
#if __has_builtin(__builtin_amdgcn_exp2f)
    return __builtin_amdgcn_exp2f(x);
#else
    extern "C" __device__ float __ocml_exp2_f32(float);
    return __ocml_exp2_f32(x);
#endif
}
__device__ __forceinline__ float rcp_(float x) { return __builtin_amdgcn_rcpf(x); }

__device__ __forceinline__ float fdot2_(u32 w, u32 h, float acc) {
#if __has_builtin(__builtin_amdgcn_fdot2)
    return __builtin_amdgcn_fdot2(__builtin_bit_cast(f16x2, w),
                                  __builtin_bit_cast(f16x2, h), acc, false);
#else
    const f16x2 a = __builtin_bit_cast(f16x2, w);
    const f16x2 b = __builtin_bit_cast(f16x2, h);
    return fmaf((float)a.y, (float)b.y, fmaf((float)a.x, (float)b.x, acc));
#endif
}

__device__ __forceinline__ float dpp_mov(float v, const int ctrl) {
    int t;
    switch (ctrl) {   // quad_perm patterns (R6-R11 verified)
      case 0x00: t = __builtin_amdgcn_update_dpp(0, __float_as_int(v), 0x00, 0xF, 0xF, true); break;
      case 0x55: t = __builtin_amdgcn_update_dpp(0, __float_as_int(v), 0x55, 0xF, 0xF, true); break;
      case 0xAA: t = __builtin_amdgcn_update_dpp(0, __float_as_int(v), 0xAA, 0xF, 0xF, true); break;
      case 0xFF: t = __builtin_amdgcn_update_dpp(0, __float_as_int(v), 0xFF, 0xF, 0xF, true); break;
      case 0xB1: t = __builtin_amdgcn_update_dpp(0, __float_as_int(v), 0xB1, 0xF, 0xF, true); break;
      default:   t = __builtin_amdgcn_update_dpp(0, __float_as_int(v), 0x4E, 0xF, 0xF, true); break;
    }
    return __int_as_float(t);
}
__device__ __forceinline__ float dpp_add(float v, const int ctrl) {
    int t;
    switch (ctrl) {
      case 0xB1:  t = __builtin_amdgcn_update_dpp(0, __float_as_int(v), 0xB1,  0xF, 0xF, true); break;
      case 0x4E:  t = __builtin_amdgcn_update_dpp(0, __float_as_int(v), 0x4E,  0xF, 0xF, true); break;
      case 0x141: t = __builtin_amdgcn_update_dpp(0, __float_as_int(v), 0x141, 0xF, 0xF, true); break;
      default:    t = __builtin_amdgcn_update_dpp(0, __float_as_int(v), 0x140, 0xF, 0xF, true); break;
    }
    return v + __int_as_float(t);
}

// swizzled LDS u32 index for the 512-thread h layout (block-rotation, R11)
__device__ __forceinline__ int hswz(int iu) {
    return (iu & 0x30) + (((((iu >> 2) & 3) + (iu >> 4)) & 3) << 2) + (iu & 3);
}

// 4x4 transpose-reduce within a quad (R11-verified)
__device__ __forceinline__ float xpose4(float a0, float a1, float a2, float a3, int q) {
    const bool qb0 = (q & 1) != 0;
    float s0, s1;
    {
        const float send = qb0 ? a0 : a1;
        s0 = (qb0 ? a1 : a0) + dpp_mov(send, 0xB1);
    }
    {
        const float send = qb0 ? a2 : a3;
        s1 = (qb0 ? a3 : a2) + dpp_mov(send, 0xB1);
    }
    const bool qb1 = (q & 2) != 0;
    const float send = qb1 ? s0 : s1;
    return (qb1 ? s1 : s0) + dpp_mov(send, 0x4E);
}

// ---------------- prep (identical to R9/R11-verified) -----------------------
__global__ void prep(const float* __restrict__ Whh0, const float* __restrict__ Whh1,
                     const float* __restrict__ Wih1, const float* __restrict__ Wih0,
                     const float* __restrict__ bih0, const float* __restrict__ bhh0,
                     const float* __restrict__ bih1, const float* __restrict__ bhh1,
                     f16* __restrict__ Wpk0, f16* __restrict__ Wpk1,
                     f16* __restrict__ W1h,  f16* __restrict__ W1l,
                     float* __restrict__ bx0, float* __restrict__ wx0,
                     float* __restrict__ b1p)
{
    const int p = blockIdx.x;       // 0..511
    const int k = threadIdx.x;      // 0..127
    const int c = p & 3, u = p >> 2;
    const int g = c * 128 + u;
    const float sc = (c == 2) ? K2L2E : -1.4426950408889634f;

    Wpk0[p * HH + k] = (f16)(Whh0[(size_t)g * HH + k] * sc);
    Wpk1[p * HH + k] = (f16)(Whh1[(size_t)g * HH + k] * sc);
    const float wf = Wih1[(size_t)g * HH + k] * sc;
    const f16 wh = (f16)wf;
    W1h[p * HH + k] = wh;
    W1l[p * HH + k] = (f16)(wf - (float)wh);
    if (k == 0) {
        bx0[p] = (bih0[g] + bhh0[g]) * sc;
        wx0[p] = Wih0[g] * sc;
        b1p[p] = (bih1[g] + bhh1[g]) * sc;
    }
}

// ============================ layer 0 =======================================
// R12's 1024-thread K-eighth kernel (bit-verified correct via R12/R13 identical
// absmax forensics). Thread = (unit u=tid>>3, slice s=tid&7): all 4 gates of u
// over K-eighth s -> 32 packed weight u32, 2 ds_read_b128 of h per step, 4
// waves/SIMD. Reduce = xpose4 (quad) + ds_swizzle xor4. h LDS padded
// 12-u32/slice (conflict-free).
__global__ __launch_bounds__(1024, 4) void lstm0(
    const float* __restrict__ x, const f16* __restrict__ Wpk0,
    const float* __restrict__ bx0, const float* __restrict__ wx0,
    f16* __restrict__ h0g)
{
    const int b = blockIdx.x;
    const int tid = threadIdx.x;
    const int u = tid >> 3, s = tid & 7;
    const int q = s & 3;
    const bool is_g = (q == 2);
    const float Ag = is_g ? -2.f : 1.f;
    const float Cg = is_g ?  1.f : 0.f;

    __shared__ __align__(16) float xS[TT];      // 4 KB
    __shared__ __align__(16) u32 hS[2][96];     // 8 slices x (8 data + 4 pad)
    __shared__ __align__(16) u16 hO[32][HH];    // 8 KB chunk staging

    xS[tid] = x[(size_t)b * TT + tid];
    if (tid < 192) ((u32*)hS)[tid] = 0u;

    // weights: gate c of unit u, f16 k in [16s,16s+16) -> u32 [8s, 8s+8)
    u32x4 Wq[4][2];
#pragma unroll
    for (int c = 0; c < 4; ++c) {
        const u32* wp = (const u32*)Wpk0 + (size_t)(4 * u + c) * 64 + s * 8;
        Wq[c][0] = *(const u32x4*)wp;
        Wq[c][1] = *(const u32x4*)(wp + 4);
    }
    const int p_lane = 4 * u + q;
    const float biasx = bx0[p_lane];
    const float wxv   = wx0[p_lane];
    float c1 = 0.f;
    __syncthreads();

    f16* og = h0g + (size_t)b * TT * HH;

#pragma unroll 1
    for (int t = 0; t < TT; ++t) {
        const u32* hcur = hS[t & 1] + s * 12;
        float a0 = 0.f, a1 = 0.f, a2 = 0.f, a3 = 0.f;
#pragma unroll
        for (int rb = 0; rb < 2; ++rb) {
            const u32x4 hq = *(const u32x4*)(hcur + rb * 4);
            a0 = fdot2_(Wq[0][rb].x, hq.x, a0); a0 = fdot2_(Wq[0][rb].y, hq.y, a0);
            a0 = fdot2_(Wq[0][rb].z, hq.z, a0); a0 = fdot2_(Wq[0][rb].w, hq.w, a0);
            a1 = fdot2_(Wq[1][rb].x, hq.x, a1); a1 = fdot2_(Wq[1][rb].y, hq.y, a1);
            a1 = fdot2_(Wq[1][rb].z, hq.z, a1); a1 = fdot2_(Wq[1][rb].w, hq.w, a1);
            a2 = fdot2_(Wq[2][rb].x, hq.x, a2); a2 = fdot2_(Wq[2][rb].y, hq.y, a2);
            a2 = fdot2_(Wq[2][rb].z, hq.z, a2); a2 = fdot2_(Wq[2][rb].w, hq.w, a2);
            a3 = fdot2_(Wq[3][rb].x, hq.x, a3); a3 = fdot2_(Wq[3][rb].y, hq.y, a3);
            a3 = fdot2_(Wq[3][rb].z, hq.z, a3); a3 = fdot2_(Wq[3][rb].w, hq.w, a3);
        }
        float V = xpose4(a0, a1, a2, a3, q);                     // quad-local sum
        V += __int_as_float(__builtin_amdgcn_ds_swizzle(__float_as_int(V), 0x101F)); // + partner quad (xor4)
        const float a = V + fmaf(xS[t], wxv, biasx);
        const float act = fmaf(Ag, rcp_(1.f + ex2(a)), Cg);
        const float gi = dpp_mov(act, 0x00);
        const float gf = dpp_mov(act, 0x55);
        const float gg = dpp_mov(act, 0xAA);
        const float go = dpp_mov(act, 0xFF);
        c1 = fmaf(gf, c1, gi * gg);
        const float h = go * fmaf(-2.f, rcp_(1.f + ex2(K2L2E * c1)), 1.f);
        if (s == 0) {
            const u16 hb = __builtin_bit_cast(u16, (f16)h);
            // padded layout: u32 idx = 12*(u>>4) + ((u>>1)&7), half = u&1
            ((u16*)hS[(t + 1) & 1])[2 * (12 * (u >> 4) + ((u >> 1) & 7)) + (u & 1)] = hb;
            hO[t & 31][u] = hb;
        }
        __syncthreads();
        if ((t & 31) == 31) {   // coalesced chunk dump (f16 hi parts)
            *(u32x2*)((u16*)og + (size_t)(t - 31) * HH + tid * 4) =
                *(const u32x2*)(&hO[0][0] + tid * 4);
            __syncthreads();
        }
    }
}

// ============================ layer 1 + FC (exact R11, passed @775us) ========
__global__ __launch_bounds__(512, 2) void lstm1(
    const f16* __restrict__ h0g, const f16* __restrict__ Wpk1,
    const f16* __restrict__ W1h, const f16* __restrict__ W1l,
    const float* __restrict__ b1p, const float* __restrict__ fcw,
    const float* __restrict__ fcb, float* __restrict__ out)
{
    const int b = blockIdx.x;
    const int tid = threadIdx.x;
    const int u = tid >> 2, q = tid & 3;
    const int wv = tid >> 6, lane = tid & 63;
    const int lr = lane & 15, lq = lane >> 4;
    const bool is_g = (q == 2);
    const float Ag = is_g ? -2.f : 1.f;
    const float Cg = is_g ?  1.f : 0.f;

    __shared__ __align__(16) float xgS[32 * 512];   // 64 KB (row-XOR swizzled)
    __shared__ __align__(16) u32 hS1[2][64];        // packed f16 h, swizzled
    __shared__ __align__(16) float fcP[32][16];     // 2 KB step partials

    if (tid < 128) ((u32*)hS1)[tid] = 0u;
    const float fcu025 = fcw[u] * 0.25f;            // quad-redundancy factor
    const float fcbv = fcb[0];
    float c1 = 0.f;
    __syncthreads();

    const f16* hb0 = h0g + (size_t)b * TT * HH;
    float* ob = out + (size_t)b * TT;

#pragma unroll 1
    for (int t0 = 0; t0 < TT; t0 += 32) {
        // ---- proj: xgS = W_ih1(permuted,split) @ h0^T + bias (R9-verified) ----
        {
            f16x8 B0[4], B1[4];
#pragma unroll
            for (int ks = 0; ks < 4; ++ks) {
                B0[ks] = *(const f16x8*)(hb0 + (size_t)(t0 + lr) * HH + ks * 32 + lq * 8);
                B1[ks] = *(const f16x8*)(hb0 + (size_t)(t0 + 16 + lr) * HH + ks * 32 + lq * 8);
            }
#pragma unroll
            for (int gtl = 0; gtl < 4; ++gtl) {
                const int g16 = (wv * 4 + gtl) * 16;
                const float4 bi = *(const float4*)&b1p[g16 + lq * 4];
                f32x4 a0 = {bi.x, bi.y, bi.z, bi.w};
                f32x4 a1 = a0;
#pragma unroll
                for (int ks = 0; ks < 4; ++ks) {
                    const f16x8 Ah = *(const f16x8*)(W1h + (size_t)(g16 + lr) * HH + ks * 32 + lq * 8);
                    const f16x8 Al = *(const f16x8*)(W1l + (size_t)(g16 + lr) * HH + ks * 32 + lq * 8);
                    a0 = MFMA16(Ah, B0[ks], a0);
                    a0 = MFMA16(Al, B0[ks], a0);
                    a1 = MFMA16(Ah, B1[ks], a1);
                    a1 = MFMA16(Al, B1[ks], a1);
                }
                const int gb = g16 + lq * 4;
                *(f32x4*)&xgS[lr * 512 + (gb ^ ((lr & 7) << 2))] = a0;
                *(f32x4*)&xgS[(16 + lr) * 512 + (gb ^ ((lr & 7) << 2))] = a1;
            }
        }
        __syncthreads();

        // reload rec weights after proj (R9/R11 pattern)
        u32x4 Wq[4][4];
        {
            const u32* wb = (const u32*)Wpk1;
            asm volatile("" : "+v"(wb));
#pragma unroll
            for (int c = 0; c < 4; ++c) {
                const u32* wp = wb + (size_t)((tid & ~3) + c) * 64 + q * 16;
#pragma unroll
                for (int rb = 0; rb < 4; ++rb) Wq[c][rb] = *(const u32x4*)(wp + rb * 4);
            }
        }

        // ---- 32 recurrent steps ----
#pragma unroll 1
        for (int i = 0; i < 32; ++i) {
            const int t = t0 + i;
            const float xgv = xgS[i * 512 + (tid ^ ((i & 7) << 2))];
            const u32* hcur = hS1[t & 1];
            float a0 = 0.f, a1 = 0.f, a2 = 0.f, a3 = 0.f;
#pragma unroll
            for (int rb = 0; rb < 4; ++rb) {
                const u32x4 hq = *(const u32x4*)(hcur + (q << 4) + (((rb + q) & 3) << 2));
                a0 = fdot2_(Wq[0][rb].x, hq.x, a0); a0 = fdot2_(Wq[0][rb].y, hq.y, a0);
                a0 = fdot2_(Wq[0][rb].z, hq.z, a0); a0 = fdot2_(Wq[0][rb].w, hq.w, a0);
                a1 = fdot2_(Wq[1][rb].x, hq.x, a1); a1 = fdot2_(Wq[1][rb].y, hq.y, a1);
                a1 = fdot2_(Wq[1][rb].z, hq.z, a1); a1 = fdot2_(Wq[1][rb].w, hq.w, a1);
                a2 = fdot2_(Wq[2][rb].x, hq.x, a2); a2 = fdot2_(Wq[2][rb].y, hq.y, a2);
                a2 = fdot2_(Wq[2][rb].z, hq.z, a2); a2 = fdot2_(Wq[2][rb].w, hq.w, a2);
                a3 = fdot2_(Wq[3][rb].x, hq.x, a3); a3 = fdot2_(Wq[3][rb].y, hq.y, a3);
                a3 = fdot2_(Wq[3][rb].z, hq.z, a3); a3 = fdot2_(Wq[3][rb].w, hq.w, a3);
            }
            const float V = xpose4(a0, a1, a2, a3, q);
            const float a = V + xgv;
            const float act = fmaf(Ag, rcp_(1.f + ex2(a)), Cg);
            const float gi = dpp_mov(act, 0x00);
            const float gf = dpp_mov(act, 0x55);
            const float gg = dpp_mov(act, 0xAA);
            const float go = dpp_mov(act, 0xFF);
            c1 = fmaf(gf, c1, gi * gg);
            const float h = go * fmaf(-2.f, rcp_(1.f + ex2(K2L2E * c1)), 1.f);
            if (q == 0)
                ((u16*)hS1[(t + 1) & 1])[2 * hswz(u >> 1) + (u & 1)] =
                    __builtin_bit_cast(u16, (f16)h);

            // FC partial: quad-redundant h, wave-local reduce, no serial chain
            float pf = h * fcu025;
            pf = dpp_add(pf, 0xB1);    // xor1
            pf = dpp_add(pf, 0x4E);    // xor2
            pf = dpp_add(pf, 0x141);   // xor4 (half-mirror, quads uniform)
            pf = dpp_add(pf, 0x140);   // xor8 (row mirror) -> 16-row sums
            pf += __int_as_float(__builtin_amdgcn_ds_swizzle(__float_as_int(pf), 0x401F)); // xor16
            if ((lane & 31) == 0) fcP[i][wv * 2 + (lane >> 5)] = pf;
            __syncthreads();
        }

        // ---- chunk-end FC gather: 32 outputs ----
        if (tid < 32) {
            float s = 0.f;
#pragma unroll
            for (int r = 0; r < 4; ++r) {
                const float4 v = *(const float4*)&fcP[tid][r * 4];
                s += (v.x + v.y) + (v.z + v.w);
            }
            ob[t0 + tid] = s + fcbv;
        }
        // ordering: gather threads pass the next proj's __syncthreads before
        // any thread can write fcP again -> no extra barrier needed
    }
}

extern "C" void kernel_launch(void* const* d_in, const int* in_sizes, int n_in,
                              void* d_out, int out_size, void* d_ws, size_t ws_size,
                              hipStream_t stream)
{
    const float* x    = (const float*)d_in[0];
    const float* Wih0 = (const float*)d_in[1];
    const float* Whh0 = (const float*)d_in[2];
    const float* bih0 = (const float*)d_in[3];
    const float* bhh0 = (const float*)d_in[4];
    const float* Wih1 = (const float*)d_in[5];
    const float* Whh1 = (const float*)d_in[6];
    const float* bih1 = (const float*)d_in[7];
    const float* bhh1 = (const float*)d_in[8];
    const float* fcw  = (const float*)d_in[9];
    const float* fcb  = (const float*)d_in[10];
    float* out = (float*)d_out;

    f16* h0g  = (f16*)d_ws;                          // 256*1024*128 f16 = 64 MiB
    f16* Wpk0 = h0g + (size_t)256 * TT * HH;         // 128 KiB each
    f16* Wpk1 = Wpk0 + 512 * HH;
    f16* W1h  = Wpk1 + 512 * HH;
    f16* W1l  = W1h + 512 * HH;
    float* bx0 = (float*)(W1l + 512 * HH);
    float* wx0 = bx0 + 512;
    float* b1p = wx0 + 512;

    prep <<<512, 128, 0, stream>>>(Whh0, Whh1, Wih1, Wih0, bih0, bhh0, bih1, bhh1,
                                   Wpk0, Wpk1, W1h, W1l, bx0, wx0, b1p);
    lstm0<<<256, 1024, 0, stream>>>(x, Wpk0, bx0, wx0, h0g);
    lstm1<<<256, 512, 0, stream>>>(h0g, Wpk1, W1h, W1l, b1p, fcw, fcb, out);
}

// Round 15
// 1393.813 us; speedup vs baseline: 1.0278x; 1.0278x over previous
//
#include <hip/hip_runtime.h>

#define TT 1024
#define HH 128

typedef unsigned int u32;
typedef unsigned short u16;
typedef _Float16 f16;
typedef f16 f16x2 __attribute__((ext_vector_type(2)));
typedef f16 f16x8 __attribute__((ext_vector_type(8)));
typedef float f32x4 __attribute__((ext_vector_type(4)));
typedef u32 u32x4 __attribute__((ext_vector_type(4)));

#define MFMA16(A, B, C) __builtin_amdgcn_mfma_f32_16x16x32_f16((A), (B), (C), 0, 0, 0)
#define K2L2E 2.8853900817779268f   /* 2*log2(e) */

__device__ __forceinline__ float ex2(float x) {
#if __has_builtin(__builtin_amdgcn_exp2f)
    return __builtin_amdgcn_exp2f(x);
#else
    extern "C" __device__ float __ocml_exp2_f32(float);
    return __ocml_exp2_f32(x);
#endif
}
__device__ __forceinline__ float rcp_(float x) { return __builtin_amdgcn_rcpf(x); }

__device__ __forceinline__ float fdot2_(u32 w, u32 h, float acc) {
#if __has_builtin(__builtin_amdgcn_fdot2)
    return __builtin_amdgcn_fdot2(__builtin_bit_cast(f16x2, w),
                                  __builtin_bit_cast(f16x2, h), acc, false);
#else
    const f16x2 a = __builtin_bit_cast(f16x2, w);
    const f16x2 b = __builtin_bit_cast(f16x2, h);
    return fmaf((float)a.y, (float)b.y, fmaf((float)a.x, (float)b.x, acc));
#endif
}

__device__ __forceinline__ float dpp_mov(float v, const int ctrl) {
    int t;
    switch (ctrl) {   // quad_perm patterns (R6-R11 verified)
      case 0x00: t = __builtin_amdgcn_update_dpp(0, __float_as_int(v), 0x00, 0xF, 0xF, true); break;
      case 0x55: t = __builtin_amdgcn_update_dpp(0, __float_as_int(v), 0x55, 0xF, 0xF, true); break;
      case 0xAA: t = __builtin_amdgcn_update_dpp(0, __float_as_int(v), 0xAA, 0xF, 0xF, true); break;
      case 0xFF: t = __builtin_amdgcn_update_dpp(0, __float_as_int(v), 0xFF, 0xF, 0xF, true); break;
      case 0xB1: t = __builtin_amdgcn_update_dpp(0, __float_as_int(v), 0xB1, 0xF, 0xF, true); break;
      default:   t = __builtin_amdgcn_update_dpp(0, __float_as_int(v), 0x4E, 0xF, 0xF, true); break;
    }
    return __int_as_float(t);
}
__device__ __forceinline__ float dpp_add(float v, const int ctrl) {
    int t;
    switch (ctrl) {
      case 0xB1:  t = __builtin_amdgcn_update_dpp(0, __float_as_int(v), 0xB1,  0xF, 0xF, true); break;
      case 0x4E:  t = __builtin_amdgcn_update_dpp(0, __float_as_int(v), 0x4E,  0xF, 0xF, true); break;
      case 0x141: t = __builtin_amdgcn_update_dpp(0, __float_as_int(v), 0x141, 0xF, 0xF, true); break;
      default:    t = __builtin_amdgcn_update_dpp(0, __float_as_int(v), 0x140, 0xF, 0xF, true); break;
    }
    return v + __int_as_float(t);
}

// swizzled LDS u32 index for the 512-thread h layout (block-rotation, R11)
__device__ __forceinline__ int hswz(int iu) {
    return (iu & 0x30) + (((((iu >> 2) & 3) + (iu >> 4)) & 3) << 2) + (iu & 3);
}

// 4x4 transpose-reduce within a quad (R11-verified)
__device__ __forceinline__ float xpose4(float a0, float a1, float a2, float a3, int q) {
    const bool qb0 = (q & 1) != 0;
    float s0, s1;
    {
        const float send = qb0 ? a0 : a1;
        s0 = (qb0 ? a1 : a0) + dpp_mov(send, 0xB1);
    }
    {
        const float send = qb0 ? a2 : a3;
        s1 = (qb0 ? a3 : a2) + dpp_mov(send, 0xB1);
    }
    const bool qb1 = (q & 2) != 0;
    const float send = qb1 ? s0 : s1;
    return (qb1 ? s1 : s0) + dpp_mov(send, 0x4E);
}

// ---------------- prep (identical to R9/R11-verified) -----------------------
__global__ void prep(const float* __restrict__ Whh0, const float* __restrict__ Whh1,
                     const float* __restrict__ Wih1, const float* __restrict__ Wih0,
                     const float* __restrict__ bih0, const float* __restrict__ bhh0,
                     const float* __restrict__ bih1, const float* __restrict__ bhh1,
                     f16* __restrict__ Wpk0, f16* __restrict__ Wpk1,
                     f16* __restrict__ W1h,  f16* __restrict__ W1l,
                     float* __restrict__ bx0, float* __restrict__ wx0,
                     float* __restrict__ b1p)
{
    const int p = blockIdx.x;       // 0..511
    const int k = threadIdx.x;      // 0..127
    const int c = p & 3, u = p >> 2;
    const int g = c * 128 + u;
    const float sc = (c == 2) ? K2L2E : -1.4426950408889634f;

    Wpk0[p * HH + k] = (f16)(Whh0[(size_t)g * HH + k] * sc);
    Wpk1[p * HH + k] = (f16)(Whh1[(size_t)g * HH + k] * sc);
    const float wf = Wih1[(size_t)g * HH + k] * sc;
    const f16 wh = (f16)wf;
    W1h[p * HH + k] = wh;
    W1l[p * HH + k] = (f16)(wf - (float)wh);
    if (k == 0) {
        bx0[p] = (bih0[g] + bhh0[g]) * sc;
        wx0[p] = Wih0[g] * sc;
        b1p[p] = (bih1[g] + bhh1[g]) * sc;
    }
}

// ================= fused producer/consumer (both R11-verified bodies) ========
// Blocks 0-255: layer-0 producer for batch b (R11 lstm0 verbatim + per-chunk
// release flag). Blocks 256-511: layer-1 consumer for batch b-256 (R11 lstm1
// verbatim + per-chunk acquire poll). Producers never wait -> deadlock-free.
__global__ __launch_bounds__(512, 4) void lstm_pc(
    const float* __restrict__ x,
    const f16* __restrict__ Wpk0, const float* __restrict__ bx0,
    const float* __restrict__ wx0, f16* __restrict__ h0g,
    const f16* __restrict__ Wpk1, const f16* __restrict__ W1h,
    const f16* __restrict__ W1l,  const float* __restrict__ b1p,
    const float* __restrict__ fcw, const float* __restrict__ fcb,
    float* __restrict__ out, int* __restrict__ flags)
{
    const int tid = threadIdx.x;

    // shared statics, overlaid between roles (74.5 KB total -> 2 blocks/CU)
    __shared__ __align__(16) float bigS[32 * 512];   // prod: xS[0..1023]; cons: xgS
    __shared__ __align__(16) u32 hSx[2][64];         // both: packed f16 h state
    __shared__ __align__(16) u16 hOx[32][HH];        // producer chunk staging
    __shared__ __align__(16) float fcPx[32][16];     // consumer FC partials

    if (blockIdx.x < 256) {
        // ======================= producer: R11 lstm0 ========================
        const int b = blockIdx.x;
        const int u = tid >> 2, q = tid & 3;
        const bool is_g = (q == 2);
        const float Ag = is_g ? -2.f : 1.f;
        const float Cg = is_g ?  1.f : 0.f;

        bigS[tid]       = x[(size_t)b * TT + tid];
        bigS[tid + 512] = x[(size_t)b * TT + tid + 512];
        if (tid < 128) ((u32*)hSx)[tid] = 0u;

        u32x4 Wq[4][4];
#pragma unroll
        for (int c = 0; c < 4; ++c) {
            const u32* wp = (const u32*)Wpk0 + (size_t)((tid & ~3) + c) * 64 + q * 16;
#pragma unroll
            for (int rb = 0; rb < 4; ++rb) Wq[c][rb] = *(const u32x4*)(wp + rb * 4);
        }
        const float biasx = bx0[tid];
        const float wxv   = wx0[tid];
        float c1 = 0.f;
        __syncthreads();

        f16* og = h0g + (size_t)b * TT * HH;

#pragma unroll 1
        for (int t = 0; t < TT; ++t) {
            const u32* hcur = hSx[t & 1];
            float a0 = 0.f, a1 = 0.f, a2 = 0.f, a3 = 0.f;
#pragma unroll
            for (int rb = 0; rb < 4; ++rb) {
                const u32x4 hq = *(const u32x4*)(hcur + (q << 4) + (((rb + q) & 3) << 2));
                a0 = fdot2_(Wq[0][rb].x, hq.x, a0); a0 = fdot2_(Wq[0][rb].y, hq.y, a0);
                a0 = fdot2_(Wq[0][rb].z, hq.z, a0); a0 = fdot2_(Wq[0][rb].w, hq.w, a0);
                a1 = fdot2_(Wq[1][rb].x, hq.x, a1); a1 = fdot2_(Wq[1][rb].y, hq.y, a1);
                a1 = fdot2_(Wq[1][rb].z, hq.z, a1); a1 = fdot2_(Wq[1][rb].w, hq.w, a1);
                a2 = fdot2_(Wq[2][rb].x, hq.x, a2); a2 = fdot2_(Wq[2][rb].y, hq.y, a2);
                a2 = fdot2_(Wq[2][rb].z, hq.z, a2); a2 = fdot2_(Wq[2][rb].w, hq.w, a2);
                a3 = fdot2_(Wq[3][rb].x, hq.x, a3); a3 = fdot2_(Wq[3][rb].y, hq.y, a3);
                a3 = fdot2_(Wq[3][rb].z, hq.z, a3); a3 = fdot2_(Wq[3][rb].w, hq.w, a3);
            }
            const float V = xpose4(a0, a1, a2, a3, q);
            const float a = V + fmaf(bigS[t], wxv, biasx);
            const float act = fmaf(Ag, rcp_(1.f + ex2(a)), Cg);
            const float gi = dpp_mov(act, 0x00);
            const float gf = dpp_mov(act, 0x55);
            const float gg = dpp_mov(act, 0xAA);
            const float go = dpp_mov(act, 0xFF);
            c1 = fmaf(gf, c1, gi * gg);
            const float h = go * fmaf(-2.f, rcp_(1.f + ex2(K2L2E * c1)), 1.f);
            if (q == 0) {
                const u16 hb = __builtin_bit_cast(u16, (f16)h);
                ((u16*)hSx[(t + 1) & 1])[2 * hswz(u >> 1) + (u & 1)] = hb;
                hOx[t & 31][u] = hb;
            }
            __syncthreads();
            if ((t & 31) == 31) {   // coalesced chunk dump + release flag
                *(u32x4*)((u16*)og + (size_t)(t - 31) * HH + tid * 8) =
                    *(const u32x4*)(&hOx[0][0] + tid * 8);
                __syncthreads();
                if (tid == 0) {
                    __threadfence();
                    __hip_atomic_store(flags + b, (t >> 5) + 1,
                                       __ATOMIC_RELEASE, __HIP_MEMORY_SCOPE_AGENT);
                }
            }
        }
    } else {
        // ===================== consumer: R11 lstm1 ==========================
        const int b = blockIdx.x - 256;
        const int u = tid >> 2, q = tid & 3;
        const int wv = tid >> 6, lane = tid & 63;
        const int lr = lane & 15, lq = lane >> 4;
        const bool is_g = (q == 2);
        const float Ag = is_g ? -2.f : 1.f;
        const float Cg = is_g ?  1.f : 0.f;

        if (tid < 128) ((u32*)hSx)[tid] = 0u;
        const float fcu025 = fcw[u] * 0.25f;
        const float fcbv = fcb[0];
        float c1 = 0.f;
        __syncthreads();

        const f16* hb0 = h0g + (size_t)b * TT * HH;
        float* ob = out + (size_t)b * TT;

#pragma unroll 1
        for (int t0 = 0; t0 < TT; t0 += 32) {
            // ---- wait for producer chunk (acquire) ----
            if (tid == 0) {
                const int need = (t0 >> 5) + 1;
                while (__hip_atomic_load(flags + b, __ATOMIC_ACQUIRE,
                                         __HIP_MEMORY_SCOPE_AGENT) < need)
                    __builtin_amdgcn_s_sleep(32);
            }
            __syncthreads();

            // ---- proj: xgS = W_ih1(permuted,split) @ h0^T + bias ----
            {
                f16x8 B0[4], B1[4];
#pragma unroll
                for (int ks = 0; ks < 4; ++ks) {
                    B0[ks] = *(const f16x8*)(hb0 + (size_t)(t0 + lr) * HH + ks * 32 + lq * 8);
                    B1[ks] = *(const f16x8*)(hb0 + (size_t)(t0 + 16 + lr) * HH + ks * 32 + lq * 8);
                }
#pragma unroll
                for (int gtl = 0; gtl < 4; ++gtl) {
                    const int g16 = (wv * 4 + gtl) * 16;
                    const float4 bi = *(const float4*)&b1p[g16 + lq * 4];
                    f32x4 a0 = {bi.x, bi.y, bi.z, bi.w};
                    f32x4 a1 = a0;
#pragma unroll
                    for (int ks = 0; ks < 4; ++ks) {
                        const f16x8 Ah = *(const f16x8*)(W1h + (size_t)(g16 + lr) * HH + ks * 32 + lq * 8);
                        const f16x8 Al = *(const f16x8*)(W1l + (size_t)(g16 + lr) * HH + ks * 32 + lq * 8);
                        a0 = MFMA16(Ah, B0[ks], a0);
                        a0 = MFMA16(Al, B0[ks], a0);
                        a1 = MFMA16(Ah, B1[ks], a1);
                        a1 = MFMA16(Al, B1[ks], a1);
                    }
                    const int gb = g16 + lq * 4;
                    *(f32x4*)&bigS[lr * 512 + (gb ^ ((lr & 7) << 2))] = a0;
                    *(f32x4*)&bigS[(16 + lr) * 512 + (gb ^ ((lr & 7) << 2))] = a1;
                }
            }
            __syncthreads();

            // reload rec weights after proj (R9/R11 pattern)
            u32x4 Wq[4][4];
            {
                const u32* wb = (const u32*)Wpk1;
                asm volatile("" : "+v"(wb));
#pragma unroll
                for (int c = 0; c < 4; ++c) {
                    const u32* wp = wb + (size_t)((tid & ~3) + c) * 64 + q * 16;
#pragma unroll
                    for (int rb = 0; rb < 4; ++rb) Wq[c][rb] = *(const u32x4*)(wp + rb * 4);
                }
            }

            // ---- 32 recurrent steps ----
#pragma unroll 1
            for (int i = 0; i < 32; ++i) {
                const int t = t0 + i;
                const float xgv = bigS[i * 512 + (tid ^ ((i & 7) << 2))];
                const u32* hcur = hSx[t & 1];
                float a0 = 0.f, a1 = 0.f, a2 = 0.f, a3 = 0.f;
#pragma unroll
                for (int rb = 0; rb < 4; ++rb) {
                    const u32x4 hq = *(const u32x4*)(hcur + (q << 4) + (((rb + q) & 3) << 2));
                    a0 = fdot2_(Wq[0][rb].x, hq.x, a0); a0 = fdot2_(Wq[0][rb].y, hq.y, a0);
                    a0 = fdot2_(Wq[0][rb].z, hq.z, a0); a0 = fdot2_(Wq[0][rb].w, hq.w, a0);
                    a1 = fdot2_(Wq[1][rb].x, hq.x, a1); a1 = fdot2_(Wq[1][rb].y, hq.y, a1);
                    a1 = fdot2_(Wq[1][rb].z, hq.z, a1); a1 = fdot2_(Wq[1][rb].w, hq.w, a1);
                    a2 = fdot2_(Wq[2][rb].x, hq.x, a2); a2 = fdot2_(Wq[2][rb].y, hq.y, a2);
                    a2 = fdot2_(Wq[2][rb].z, hq.z, a2); a2 = fdot2_(Wq[2][rb].w, hq.w, a2);
                    a3 = fdot2_(Wq[3][rb].x, hq.x, a3); a3 = fdot2_(Wq[3][rb].y, hq.y, a3);
                    a3 = fdot2_(Wq[3][rb].z, hq.z, a3); a3 = fdot2_(Wq[3][rb].w, hq.w, a3);
                }
                const float V = xpose4(a0, a1, a2, a3, q);
                const float a = V + xgv;
                const float act = fmaf(Ag, rcp_(1.f + ex2(a)), Cg);
                const float gi = dpp_mov(act, 0x00);
                const float gf = dpp_mov(act, 0x55);
                const float gg = dpp_mov(act, 0xAA);
                const float go = dpp_mov(act, 0xFF);
                c1 = fmaf(gf, c1, gi * gg);
                const float h = go * fmaf(-2.f, rcp_(1.f + ex2(K2L2E * c1)), 1.f);
                if (q == 0)
                    ((u16*)hSx[(t + 1) & 1])[2 * hswz(u >> 1) + (u & 1)] =
                        __builtin_bit_cast(u16, (f16)h);

                float pf = h * fcu025;
                pf = dpp_add(pf, 0xB1);    // xor1
                pf = dpp_add(pf, 0x4E);    // xor2
                pf = dpp_add(pf, 0x141);   // xor4
                pf = dpp_add(pf, 0x140);   // xor8 -> 16-row sums
                pf += __int_as_float(__builtin_amdgcn_ds_swizzle(__float_as_int(pf), 0x401F)); // xor16
                if ((lane & 31) == 0) fcPx[i][wv * 2 + (lane >> 5)] = pf;
                __syncthreads();
            }

            // ---- chunk-end FC gather: 32 outputs ----
            if (tid < 32) {
                float s = 0.f;
#pragma unroll
                for (int r = 0; r < 4; ++r) {
                    const float4 v = *(const float4*)&fcPx[tid][r * 4];
                    s += (v.x + v.y) + (v.z + v.w);
                }
                ob[t0 + tid] = s + fcbv;
            }
        }
    }
}

extern "C" void kernel_launch(void* const* d_in, const int* in_sizes, int n_in,
                              void* d_out, int out_size, void* d_ws, size_t ws_size,
                              hipStream_t stream)
{
    const float* x    = (const float*)d_in[0];
    const float* Wih0 = (const float*)d_in[1];
    const float* Whh0 = (const float*)d_in[2];
    const float* bih0 = (const float*)d_in[3];
    const float* bhh0 = (const float*)d_in[4];
    const float* Wih1 = (const float*)d_in[5];
    const float* Whh1 = (const float*)d_in[6];
    const float* bih1 = (const float*)d_in[7];
    const float* bhh1 = (const float*)d_in[8];
    const float* fcw  = (const float*)d_in[9];
    const float* fcb  = (const float*)d_in[10];
    float* out = (float*)d_out;

    f16* h0g  = (f16*)d_ws;                          // 256*1024*128 f16 = 64 MiB
    f16* Wpk0 = h0g + (size_t)256 * TT * HH;         // 128 KiB each
    f16* Wpk1 = Wpk0 + 512 * HH;
    f16* W1h  = Wpk1 + 512 * HH;
    f16* W1l  = W1h + 512 * HH;
    float* bx0 = (float*)(W1l + 512 * HH);
    float* wx0 = bx0 + 512;
    float* b1p = wx0 + 512;
    int* flags = (int*)(b1p + 512);                  // 256 ints

    hipMemsetAsync(flags, 0, 256 * sizeof(int), stream);
    prep<<<512, 128, 0, stream>>>(Whh0, Whh1, Wih1, Wih0, bih0, bhh0, bih1, bhh1,
                                  Wpk0, Wpk1, W1h, W1l, bx0, wx0, b1p);
    lstm_pc<<<512, 512, 0, stream>>>(x, Wpk0, bx0, wx0, h0g, Wpk1, W1h, W1l, b1p,
                                     fcw, fcb, out, flags);
}

// Round 16
// 1304.025 us; speedup vs baseline: 1.0986x; 1.0689x over previous
//
#include <hip/hip_runtime.h>

#define TT 1024
#define HH 128

typedef unsigned int u32;
typedef unsigned short u16;
typedef _Float16 f16;
typedef f16 f16x2 __attribute__((ext_vector_type(2)));
typedef f16 f16x8 __attribute__((ext_vector_type(8)));
typedef float f32x4 __attribute__((ext_vector_type(4)));
typedef u32 u32x4 __attribute__((ext_vector_type(4)));

#define MFMA16(A, B, C) __builtin_amdgcn_mfma_f32_16x16x32_f16((A), (B), (C), 0, 0, 0)
#define K2L2E 2.8853900817779268f   /* 2*log2(e) */

__device__ __forceinline__ float ex2(float x) {
#if __has_builtin(__builtin_amdgcn_exp2f)
    return __builtin_amdgcn_exp2f(x);
#else
    extern "C" __device__ float __ocml_exp2_f32(float);
    return __ocml_exp2_f32(x);
#endif
}
__device__ __forceinline__ float rcp_(float x) { return __builtin_amdgcn_rcpf(x); }

__device__ __forceinline__ float fdot2_(u32 w, u32 h, float acc) {
#if __has_builtin(__builtin_amdgcn_fdot2)
    return __builtin_amdgcn_fdot2(__builtin_bit_cast(f16x2, w),
                                  __builtin_bit_cast(f16x2, h), acc, false);
#else
    const f16x2 a = __builtin_bit_cast(f16x2, w);
    const f16x2 b = __builtin_bit_cast(f16x2, h);
    return fmaf((float)a.y, (float)b.y, fmaf((float)a.x, (float)b.x, acc));
#endif
}

__device__ __forceinline__ float dpp_mov(float v, const int ctrl) {
    int t;
    switch (ctrl) {   // quad_perm patterns (R6-R14 verified)
      case 0x00: t = __builtin_amdgcn_update_dpp(0, __float_as_int(v), 0x00, 0xF, 0xF, true); break;
      case 0x55: t = __builtin_amdgcn_update_dpp(0, __float_as_int(v), 0x55, 0xF, 0xF, true); break;
      case 0xAA: t = __builtin_amdgcn_update_dpp(0, __float_as_int(v), 0xAA, 0xF, 0xF, true); break;
      case 0xFF: t = __builtin_amdgcn_update_dpp(0, __float_as_int(v), 0xFF, 0xF, 0xF, true); break;
      case 0xB1: t = __builtin_amdgcn_update_dpp(0, __float_as_int(v), 0xB1, 0xF, 0xF, true); break;
      default:   t = __builtin_amdgcn_update_dpp(0, __float_as_int(v), 0x4E, 0xF, 0xF, true); break;
    }
    return __int_as_float(t);
}
__device__ __forceinline__ float dpp_add(float v, const int ctrl) {
    int t;
    switch (ctrl) {
      case 0xB1:  t = __builtin_amdgcn_update_dpp(0, __float_as_int(v), 0xB1,  0xF, 0xF, true); break;
      case 0x4E:  t = __builtin_amdgcn_update_dpp(0, __float_as_int(v), 0x4E,  0xF, 0xF, true); break;
      case 0x141: t = __builtin_amdgcn_update_dpp(0, __float_as_int(v), 0x141, 0xF, 0xF, true); break;
      default:    t = __builtin_amdgcn_update_dpp(0, __float_as_int(v), 0x140, 0xF, 0xF, true); break;
    }
    return v + __int_as_float(t);
}
__device__ __forceinline__ float swz_xor4(float v) {
    return __int_as_float(__builtin_amdgcn_ds_swizzle(__float_as_int(v), 0x101F));
}

// swizzled LDS u32 index for the 512-thread K-quarter h layout (R11 lstm0)
__device__ __forceinline__ int hswz(int iu) {
    return (iu & 0x30) + (((((iu >> 2) & 3) + (iu >> 4)) & 3) << 2) + (iu & 3);
}

// 4x4 transpose-reduce within a quad (R11-verified, used by lstm0)
__device__ __forceinline__ float xpose4(float a0, float a1, float a2, float a3, int q) {
    const bool qb0 = (q & 1) != 0;
    float s0, s1;
    {
        const float send = qb0 ? a0 : a1;
        s0 = (qb0 ? a1 : a0) + dpp_mov(send, 0xB1);
    }
    {
        const float send = qb0 ? a2 : a3;
        s1 = (qb0 ? a3 : a2) + dpp_mov(send, 0xB1);
    }
    const bool qb1 = (q & 2) != 0;
    const float send = qb1 ? s0 : s1;
    return (qb1 ? s1 : s0) + dpp_mov(send, 0x4E);
}

// ---------------- prep (identical to R9/R11-verified) -----------------------
__global__ void prep(const float* __restrict__ Whh0, const float* __restrict__ Whh1,
                     const float* __restrict__ Wih1, const float* __restrict__ Wih0,
                     const float* __restrict__ bih0, const float* __restrict__ bhh0,
                     const float* __restrict__ bih1, const float* __restrict__ bhh1,
                     f16* __restrict__ Wpk0, f16* __restrict__ Wpk1,
                     f16* __restrict__ W1h,  f16* __restrict__ W1l,
                     float* __restrict__ bx0, float* __restrict__ wx0,
                     float* __restrict__ b1p)
{
    const int p = blockIdx.x;       // 0..511
    const int k = threadIdx.x;      // 0..127
    const int c = p & 3, u = p >> 2;
    const int g = c * 128 + u;
    const float sc = (c == 2) ? K2L2E : -1.4426950408889634f;

    Wpk0[p * HH + k] = (f16)(Whh0[(size_t)g * HH + k] * sc);
    Wpk1[p * HH + k] = (f16)(Whh1[(size_t)g * HH + k] * sc);
    const float wf = Wih1[(size_t)g * HH + k] * sc;
    const f16 wh = (f16)wf;
    W1h[p * HH + k] = wh;
    W1l[p * HH + k] = (f16)(wf - (float)wh);
    if (k == 0) {
        bx0[p] = (bih0[g] + bhh0[g]) * sc;
        wx0[p] = Wih0[g] * sc;
        b1p[p] = (bih1[g] + bhh1[g]) * sc;
    }
}

// ============================ layer 0 (exact R11, passed @480us) =============
__global__ __launch_bounds__(512, 2) void lstm0(
    const float* __restrict__ x, const f16* __restrict__ Wpk0,
    const float* __restrict__ bx0, const float* __restrict__ wx0,
    f16* __restrict__ h0g)
{
    const int b = blockIdx.x;
    const int tid = threadIdx.x;
    const int u = tid >> 2, q = tid & 3;
    const bool is_g = (q == 2);
    const float Ag = is_g ? -2.f : 1.f;
    const float Cg = is_g ?  1.f : 0.f;

    __shared__ __align__(16) float xS[TT];          // 4 KB
    __shared__ __align__(16) u32 hS[2][64];         // packed f16 h, swizzled
    __shared__ __align__(16) u16 hO[32][HH];        // 8 KB chunk staging

    xS[tid]       = x[(size_t)b * TT + tid];
    xS[tid + 512] = x[(size_t)b * TT + tid + 512];
    if (tid < 128) ((u32*)hS)[tid] = 0u;

    u32x4 Wq[4][4];
#pragma unroll
    for (int c = 0; c < 4; ++c) {
        const u32* wp = (const u32*)Wpk0 + (size_t)((tid & ~3) + c) * 64 + q * 16;
#pragma unroll
        for (int rb = 0; rb < 4; ++rb) Wq[c][rb] = *(const u32x4*)(wp + rb * 4);
    }
    const float biasx = bx0[tid];
    const float wxv   = wx0[tid];
    float c1 = 0.f;
    __syncthreads();

    f16* og = h0g + (size_t)b * TT * HH;

#pragma unroll 1
    for (int t = 0; t < TT; ++t) {
        const u32* hcur = hS[t & 1];
        float a0 = 0.f, a1 = 0.f, a2 = 0.f, a3 = 0.f;
#pragma unroll
        for (int rb = 0; rb < 4; ++rb) {
            const u32x4 hq = *(const u32x4*)(hcur + (q << 4) + (((rb + q) & 3) << 2));
            a0 = fdot2_(Wq[0][rb].x, hq.x, a0); a0 = fdot2_(Wq[0][rb].y, hq.y, a0);
            a0 = fdot2_(Wq[0][rb].z, hq.z, a0); a0 = fdot2_(Wq[0][rb].w, hq.w, a0);
            a1 = fdot2_(Wq[1][rb].x, hq.x, a1); a1 = fdot2_(Wq[1][rb].y, hq.y, a1);
            a1 = fdot2_(Wq[1][rb].z, hq.z, a1); a1 = fdot2_(Wq[1][rb].w, hq.w, a1);
            a2 = fdot2_(Wq[2][rb].x, hq.x, a2); a2 = fdot2_(Wq[2][rb].y, hq.y, a2);
            a2 = fdot2_(Wq[2][rb].z, hq.z, a2); a2 = fdot2_(Wq[2][rb].w, hq.w, a2);
            a3 = fdot2_(Wq[3][rb].x, hq.x, a3); a3 = fdot2_(Wq[3][rb].y, hq.y, a3);
            a3 = fdot2_(Wq[3][rb].z, hq.z, a3); a3 = fdot2_(Wq[3][rb].w, hq.w, a3);
        }
        const float V = xpose4(a0, a1, a2, a3, q);
        const float a = V + fmaf(xS[t], wxv, biasx);
        const float act = fmaf(Ag, rcp_(1.f + ex2(a)), Cg);
        const float gi = dpp_mov(act, 0x00);
        const float gf = dpp_mov(act, 0x55);
        const float gg = dpp_mov(act, 0xAA);
        const float go = dpp_mov(act, 0xFF);
        c1 = fmaf(gf, c1, gi * gg);
        const float h = go * fmaf(-2.f, rcp_(1.f + ex2(K2L2E * c1)), 1.f);
        if (q == 0) {
            const u16 hb = __builtin_bit_cast(u16, (f16)h);
            ((u16*)hS[(t + 1) & 1])[2 * hswz(u >> 1) + (u & 1)] = hb;
            hO[t & 31][u] = hb;
        }
        __syncthreads();
        if ((t & 31) == 31) {   // coalesced chunk dump of h0 (f16 hi parts)
            *(u32x4*)((u16*)og + (size_t)(t - 31) * HH + tid * 8) =
                *(const u32x4*)(&hO[0][0] + tid * 8);
            __syncthreads();
        }
    }
}

// ============================ layer 1 + FC ==================================
// K-EIGHTH core at 512 threads: thread = (unit pair p=tid>>3, slice s=tid&7).
// 2 units x 4 gates x K/8 -> 64 weight u32 (residency proven), only 2
// ds_read_b128 of h per step (half of R11), 8-deep dot chains. h layout =
// R12's bit-verified padded [2][96]. Reduce = 8x8 select-exchange transpose
// (dpp xor1, dpp xor2, ds_swizzle xor4): lane s ends with gate s&3 of unit
// 2p+(s>>2). Proj / xgS read (index==tid) / FC chain: R11-verbatim.
__global__ __launch_bounds__(512, 2) void lstm1(
    const f16* __restrict__ h0g, const f16* __restrict__ Wpk1,
    const f16* __restrict__ W1h, const f16* __restrict__ W1l,
    const float* __restrict__ b1p, const float* __restrict__ fcw,
    const float* __restrict__ fcb, float* __restrict__ out)
{
    const int b = blockIdx.x;
    const int tid = threadIdx.x;
    const int p = tid >> 3, s = tid & 7;
    const int q = s & 3, half = s >> 2;
    const int ul = 2 * p + half;                    // this lane's unit
    const int wv = tid >> 6, lane = tid & 63;
    const int lr = lane & 15, lq = lane >> 4;
    const bool is_g = (q == 2);
    const float Ag = is_g ? -2.f : 1.f;
    const float Cg = is_g ?  1.f : 0.f;

    __shared__ __align__(16) float xgS[32 * 512];   // 64 KB (row-XOR swizzled)
    __shared__ __align__(16) u32 hS1[2][96];        // 8 slices x (8 data + 4 pad)
    __shared__ __align__(16) float fcP[32][16];     // 2 KB step partials

    if (tid < 192) ((u32*)hS1)[tid] = 0u;
    const float fcu025 = fcw[ul] * 0.25f;           // quad-redundancy factor
    const float fcbv = fcb[0];
    float c1 = 0.f;
    __syncthreads();

    const f16* hb0 = h0g + (size_t)b * TT * HH;
    float* ob = out + (size_t)b * TT;

#pragma unroll 1
    for (int t0 = 0; t0 < TT; t0 += 32) {
        // ---- proj: xgS = W_ih1(permuted,split) @ h0^T + bias (R9-verified) ----
        {
            f16x8 B0[4], B1[4];
#pragma unroll
            for (int ks = 0; ks < 4; ++ks) {
                B0[ks] = *(const f16x8*)(hb0 + (size_t)(t0 + lr) * HH + ks * 32 + lq * 8);
                B1[ks] = *(const f16x8*)(hb0 + (size_t)(t0 + 16 + lr) * HH + ks * 32 + lq * 8);
            }
#pragma unroll
            for (int gtl = 0; gtl < 4; ++gtl) {
                const int g16 = (wv * 4 + gtl) * 16;
                const float4 bi = *(const float4*)&b1p[g16 + lq * 4];
                f32x4 a0 = {bi.x, bi.y, bi.z, bi.w};
                f32x4 a1 = a0;
#pragma unroll
                for (int ks = 0; ks < 4; ++ks) {
                    const f16x8 Ah = *(const f16x8*)(W1h + (size_t)(g16 + lr) * HH + ks * 32 + lq * 8);
                    const f16x8 Al = *(const f16x8*)(W1l + (size_t)(g16 + lr) * HH + ks * 32 + lq * 8);
                    a0 = MFMA16(Ah, B0[ks], a0);
                    a0 = MFMA16(Al, B0[ks], a0);
                    a1 = MFMA16(Ah, B1[ks], a1);
                    a1 = MFMA16(Al, B1[ks], a1);
                }
                const int gb = g16 + lq * 4;
                *(f32x4*)&xgS[lr * 512 + (gb ^ ((lr & 7) << 2))] = a0;
                *(f32x4*)&xgS[(16 + lr) * 512 + (gb ^ ((lr & 7) << 2))] = a1;
            }
        }
        __syncthreads();

        // reload rec weights after proj (R9/R11 pattern)
        // Wq[e][c][rb]: gate c of unit 2p+e, u32 [s*8 + rb*4, +4)
        u32x4 Wq[2][4][2];
        {
            const u32* wb = (const u32*)Wpk1;
            asm volatile("" : "+v"(wb));
#pragma unroll
            for (int e = 0; e < 2; ++e)
#pragma unroll
                for (int c = 0; c < 4; ++c) {
                    const u32* wp = wb + (size_t)(4 * (2 * p + e) + c) * 64 + s * 8;
                    Wq[e][c][0] = *(const u32x4*)wp;
                    Wq[e][c][1] = *(const u32x4*)(wp + 4);
                }
        }

        // ---- 32 recurrent steps ----
#pragma unroll 1
        for (int i = 0; i < 32; ++i) {
            const int t = t0 + i;
            const float xgv = xgS[i * 512 + (tid ^ ((i & 7) << 2))];
            const u32* hcur = hS1[t & 1] + s * 12;
            float acc[2][4] = {};
#pragma unroll
            for (int rb = 0; rb < 2; ++rb) {
                const u32x4 hq = *(const u32x4*)(hcur + rb * 4);
#pragma unroll
                for (int e = 0; e < 2; ++e) {
                    acc[e][0] = fdot2_(Wq[e][0][rb].x, hq.x, acc[e][0]);
                    acc[e][0] = fdot2_(Wq[e][0][rb].y, hq.y, acc[e][0]);
                    acc[e][0] = fdot2_(Wq[e][0][rb].z, hq.z, acc[e][0]);
                    acc[e][0] = fdot2_(Wq[e][0][rb].w, hq.w, acc[e][0]);
                    acc[e][1] = fdot2_(Wq[e][1][rb].x, hq.x, acc[e][1]);
                    acc[e][1] = fdot2_(Wq[e][1][rb].y, hq.y, acc[e][1]);
                    acc[e][1] = fdot2_(Wq[e][1][rb].z, hq.z, acc[e][1]);
                    acc[e][1] = fdot2_(Wq[e][1][rb].w, hq.w, acc[e][1]);
                    acc[e][2] = fdot2_(Wq[e][2][rb].x, hq.x, acc[e][2]);
                    acc[e][2] = fdot2_(Wq[e][2][rb].y, hq.y, acc[e][2]);
                    acc[e][2] = fdot2_(Wq[e][2][rb].z, hq.z, acc[e][2]);
                    acc[e][2] = fdot2_(Wq[e][2][rb].w, hq.w, acc[e][2]);
                    acc[e][3] = fdot2_(Wq[e][3][rb].x, hq.x, acc[e][3]);
                    acc[e][3] = fdot2_(Wq[e][3][rb].y, hq.y, acc[e][3]);
                    acc[e][3] = fdot2_(Wq[e][3][rb].z, hq.z, acc[e][3]);
                    acc[e][3] = fdot2_(Wq[e][3][rb].w, hq.w, acc[e][3]);
                }
            }

            // ---- 8x8 select-exchange transpose-reduce over the 8 slices ----
            // stage 1: xor1 (gate bit0 <-> lane bit0)
            const bool b0 = (s & 1) != 0;
            float w4[4];
#pragma unroll
            for (int jj = 0; jj < 4; ++jj) {
                const int e = jj >> 1, ch = (jj & 1) * 2;
                const float keep = b0 ? acc[e][ch + 1] : acc[e][ch];
                const float send = b0 ? acc[e][ch]     : acc[e][ch + 1];
                w4[jj] = keep + dpp_mov(send, 0xB1);
            }
            // stage 2: xor2 (gate bit1 <-> lane bit1)
            const bool b1 = (s & 2) != 0;
            float x2[2];
#pragma unroll
            for (int kk = 0; kk < 2; ++kk) {
                const float keep = b1 ? w4[kk * 2 + 1] : w4[kk * 2];
                const float send = b1 ? w4[kk * 2]     : w4[kk * 2 + 1];
                x2[kk] = keep + dpp_mov(send, 0x4E);
            }
            // stage 3: xor4 (unit-in-pair <-> lane bit2), via ds_swizzle
            const bool b2 = half != 0;
            const float keep3 = b2 ? x2[1] : x2[0];
            const float send3 = b2 ? x2[0] : x2[1];
            const float V = keep3 + swz_xor4(send3);

            const float a = V + xgv;
            const float act = fmaf(Ag, rcp_(1.f + ex2(a)), Cg);
            const float gi = dpp_mov(act, 0x00);
            const float gf = dpp_mov(act, 0x55);
            const float gg = dpp_mov(act, 0xAA);
            const float go = dpp_mov(act, 0xFF);
            c1 = fmaf(gf, c1, gi * gg);
            const float h = go * fmaf(-2.f, rcp_(1.f + ex2(K2L2E * c1)), 1.f);
            if (q == 0) {   // lanes s==0 (unit 2p) and s==4 (unit 2p+1) write
                ((u16*)hS1[(t + 1) & 1])[2 * (12 * (ul >> 4) + ((ul >> 1) & 7)) + (ul & 1)] =
                    __builtin_bit_cast(u16, (f16)h);
            }

            // FC partial (R11-verbatim): h replicated x4 in quad
            float pf = h * fcu025;
            pf = dpp_add(pf, 0xB1);    // xor1
            pf = dpp_add(pf, 0x4E);    // xor2
            pf = dpp_add(pf, 0x141);   // xor4 (half-mirror, quads uniform)
            pf = dpp_add(pf, 0x140);   // xor8 (row mirror) -> 16-row sums
            pf += __int_as_float(__builtin_amdgcn_ds_swizzle(__float_as_int(pf), 0x401F)); // xor16
            if ((lane & 31) == 0) fcP[i][wv * 2 + (lane >> 5)] = pf;
            __syncthreads();
        }

        // ---- chunk-end FC gather: 32 outputs ----
        if (tid < 32) {
            float sacc = 0.f;
#pragma unroll
            for (int r = 0; r < 4; ++r) {
                const float4 v = *(const float4*)&fcP[tid][r * 4];
                sacc += (v.x + v.y) + (v.z + v.w);
            }
            ob[t0 + tid] = sacc + fcbv;
        }
        // gather threads pass the next proj's __syncthreads before any thread
        // can rewrite fcP -> no extra barrier needed (R11-verified ordering)
    }
}

extern "C" void kernel_launch(void* const* d_in, const int* in_sizes, int n_in,
                              void* d_out, int out_size, void* d_ws, size_t ws_size,
                              hipStream_t stream)
{
    const float* x    = (const float*)d_in[0];
    const float* Wih0 = (const float*)d_in[1];
    const float* Whh0 = (const float*)d_in[2];
    const float* bih0 = (const float*)d_in[3];
    const float* bhh0 = (const float*)d_in[4];
    const float* Wih1 = (const float*)d_in[5];
    const float* Whh1 = (const float*)d_in[6];
    const float* bih1 = (const float*)d_in[7];
    const float* bhh1 = (const float*)d_in[8];
    const float* fcw  = (const float*)d_in[9];
    const float* fcb  = (const float*)d_in[10];
    float* out = (float*)d_out;

    f16* h0g  = (f16*)d_ws;                          // 256*1024*128 f16 = 64 MiB
    f16* Wpk0 = h0g + (size_t)256 * TT * HH;         // 128 KiB each
    f16* Wpk1 = Wpk0 + 512 * HH;
    f16* W1h  = Wpk1 + 512 * HH;
    f16* W1l  = W1h + 512 * HH;
    float* bx0 = (float*)(W1l + 512 * HH);
    float* wx0 = bx0 + 512;
    float* b1p = wx0 + 512;

    prep <<<512, 128, 0, stream>>>(Whh0, Whh1, Wih1, Wih0, bih0, bhh0, bih1, bhh1,
                                   Wpk0, Wpk1, W1h, W1l, bx0, wx0, b1p);
    lstm0<<<256, 512, 0, stream>>>(x, Wpk0, bx0, wx0, h0g);
    lstm1<<<256, 512, 0, stream>>>(h0g, Wpk1, W1h, W1l, b1p, fcw, fcb, out);
}

// Round 17
// 1299.892 us; speedup vs baseline: 1.1021x; 1.0032x over previous
//
#include <hip/hip_runtime.h>

#define TT 1024
#define HH 128

typedef unsigned int u32;
typedef unsigned short u16;
typedef _Float16 f16;
typedef f16 f16x2 __attribute__((ext_vector_type(2)));
typedef f16 f16x8 __attribute__((ext_vector_type(8)));
typedef float f32x4 __attribute__((ext_vector_type(4)));
typedef u32 u32x4 __attribute__((ext_vector_type(4)));

#define MFMA16(A, B, C) __builtin_amdgcn_mfma_f32_16x16x32_f16((A), (B), (C), 0, 0, 0)
#define K2L2E 2.8853900817779268f   /* 2*log2(e) */

__device__ __forceinline__ float ex2(float x) {
#if __has_builtin(__builtin_amdgcn_exp2f)
    return __builtin_amdgcn_exp2f(x);
#else
    extern "C" __device__ float __ocml_exp2_f32(float);
    return __ocml_exp2_f32(x);
#endif
}
__device__ __forceinline__ float rcp_(float x) { return __builtin_amdgcn_rcpf(x); }

__device__ __forceinline__ float fdot2_(u32 w, u32 h, float acc) {
#if __has_builtin(__builtin_amdgcn_fdot2)
    return __builtin_amdgcn_fdot2(__builtin_bit_cast(f16x2, w),
                                  __builtin_bit_cast(f16x2, h), acc, false);
#else
    const f16x2 a = __builtin_bit_cast(f16x2, w);
    const f16x2 b = __builtin_bit_cast(f16x2, h);
    return fmaf((float)a.y, (float)b.y, fmaf((float)a.x, (float)b.x, acc));
#endif
}

__device__ __forceinline__ float dpp_mov(float v, const int ctrl) {
    int t;
    switch (ctrl) {   // quad_perm patterns (R6-R16 verified)
      case 0x00: t = __builtin_amdgcn_update_dpp(0, __float_as_int(v), 0x00, 0xF, 0xF, true); break;
      case 0x55: t = __builtin_amdgcn_update_dpp(0, __float_as_int(v), 0x55, 0xF, 0xF, true); break;
      case 0xAA: t = __builtin_amdgcn_update_dpp(0, __float_as_int(v), 0xAA, 0xF, 0xF, true); break;
      case 0xFF: t = __builtin_amdgcn_update_dpp(0, __float_as_int(v), 0xFF, 0xF, 0xF, true); break;
      case 0xB1: t = __builtin_amdgcn_update_dpp(0, __float_as_int(v), 0xB1, 0xF, 0xF, true); break;
      default:   t = __builtin_amdgcn_update_dpp(0, __float_as_int(v), 0x4E, 0xF, 0xF, true); break;
    }
    return __int_as_float(t);
}
__device__ __forceinline__ float dpp_add(float v, const int ctrl) {
    int t;
    switch (ctrl) {
      case 0xB1:  t = __builtin_amdgcn_update_dpp(0, __float_as_int(v), 0xB1,  0xF, 0xF, true); break;
      case 0x4E:  t = __builtin_amdgcn_update_dpp(0, __float_as_int(v), 0x4E,  0xF, 0xF, true); break;
      case 0x141: t = __builtin_amdgcn_update_dpp(0, __float_as_int(v), 0x141, 0xF, 0xF, true); break;
      default:    t = __builtin_amdgcn_update_dpp(0, __float_as_int(v), 0x140, 0xF, 0xF, true); break;
    }
    return v + __int_as_float(t);
}

// swizzled LDS u32 index for the 512-thread K-quarter h layout (R11)
__device__ __forceinline__ int hswz(int iu) {
    return (iu & 0x30) + (((((iu >> 2) & 3) + (iu >> 4)) & 3) << 2) + (iu & 3);
}

// 4x4 transpose-reduce within a quad (R11-verified)
__device__ __forceinline__ float xpose4(float a0, float a1, float a2, float a3, int q) {
    const bool qb0 = (q & 1) != 0;
    float s0, s1;
    {
        const float send = qb0 ? a0 : a1;
        s0 = (qb0 ? a1 : a0) + dpp_mov(send, 0xB1);
    }
    {
        const float send = qb0 ? a2 : a3;
        s1 = (qb0 ? a3 : a2) + dpp_mov(send, 0xB1);
    }
    const bool qb1 = (q & 2) != 0;
    const float send = qb1 ? s0 : s1;
    return (qb1 ? s1 : s0) + dpp_mov(send, 0x4E);
}

// ---------------- prep (identical to R9/R11-verified) -----------------------
__global__ void prep(const float* __restrict__ Whh0, const float* __restrict__ Whh1,
                     const float* __restrict__ Wih1, const float* __restrict__ Wih0,
                     const float* __restrict__ bih0, const float* __restrict__ bhh0,
                     const float* __restrict__ bih1, const float* __restrict__ bhh1,
                     f16* __restrict__ Wpk0, f16* __restrict__ Wpk1,
                     f16* __restrict__ W1h,  f16* __restrict__ W1l,
                     float* __restrict__ bx0, float* __restrict__ wx0,
                     float* __restrict__ b1p)
{
    const int p = blockIdx.x;       // 0..511
    const int k = threadIdx.x;      // 0..127
    const int c = p & 3, u = p >> 2;
    const int g = c * 128 + u;
    const float sc = (c == 2) ? K2L2E : -1.4426950408889634f;

    Wpk0[p * HH + k] = (f16)(Whh0[(size_t)g * HH + k] * sc);
    Wpk1[p * HH + k] = (f16)(Whh1[(size_t)g * HH + k] * sc);
    const float wf = Wih1[(size_t)g * HH + k] * sc;
    const f16 wh = (f16)wf;
    W1h[p * HH + k] = wh;
    W1l[p * HH + k] = (f16)(wf - (float)wh);
    if (k == 0) {
        bx0[p] = (bih0[g] + bhh0[g]) * sc;
        wx0[p] = Wih0[g] * sc;
        b1p[p] = (bih1[g] + bhh1[g]) * sc;
    }
}

// ============================ layer 0 (exact R11, passed @480us) =============
__global__ __launch_bounds__(512, 2) void lstm0(
    const float* __restrict__ x, const f16* __restrict__ Wpk0,
    const float* __restrict__ bx0, const float* __restrict__ wx0,
    f16* __restrict__ h0g)
{
    const int b = blockIdx.x;
    const int tid = threadIdx.x;
    const int u = tid >> 2, q = tid & 3;
    const bool is_g = (q == 2);
    const float Ag = is_g ? -2.f : 1.f;
    const float Cg = is_g ?  1.f : 0.f;

    __shared__ __align__(16) float xS[TT];          // 4 KB
    __shared__ __align__(16) u32 hS[2][64];         // packed f16 h, swizzled
    __shared__ __align__(16) u16 hO[32][HH];        // 8 KB chunk staging

    xS[tid]       = x[(size_t)b * TT + tid];
    xS[tid + 512] = x[(size_t)b * TT + tid + 512];
    if (tid < 128) ((u32*)hS)[tid] = 0u;

    u32x4 Wq[4][4];
#pragma unroll
    for (int c = 0; c < 4; ++c) {
        const u32* wp = (const u32*)Wpk0 + (size_t)((tid & ~3) + c) * 64 + q * 16;
#pragma unroll
        for (int rb = 0; rb < 4; ++rb) Wq[c][rb] = *(const u32x4*)(wp + rb * 4);
    }
    const float biasx = bx0[tid];
    const float wxv   = wx0[tid];
    float c1 = 0.f;
    __syncthreads();

    f16* og = h0g + (size_t)b * TT * HH;

#pragma unroll 1
    for (int t = 0; t < TT; ++t) {
        const u32* hcur = hS[t & 1];
        float a0 = 0.f, a1 = 0.f, a2 = 0.f, a3 = 0.f;
#pragma unroll
        for (int rb = 0; rb < 4; ++rb) {
            const u32x4 hq = *(const u32x4*)(hcur + (q << 4) + (((rb + q) & 3) << 2));
            a0 = fdot2_(Wq[0][rb].x, hq.x, a0); a0 = fdot2_(Wq[0][rb].y, hq.y, a0);
            a0 = fdot2_(Wq[0][rb].z, hq.z, a0); a0 = fdot2_(Wq[0][rb].w, hq.w, a0);
            a1 = fdot2_(Wq[1][rb].x, hq.x, a1); a1 = fdot2_(Wq[1][rb].y, hq.y, a1);
            a1 = fdot2_(Wq[1][rb].z, hq.z, a1); a1 = fdot2_(Wq[1][rb].w, hq.w, a1);
            a2 = fdot2_(Wq[2][rb].x, hq.x, a2); a2 = fdot2_(Wq[2][rb].y, hq.y, a2);
            a2 = fdot2_(Wq[2][rb].z, hq.z, a2); a2 = fdot2_(Wq[2][rb].w, hq.w, a2);
            a3 = fdot2_(Wq[3][rb].x, hq.x, a3); a3 = fdot2_(Wq[3][rb].y, hq.y, a3);
            a3 = fdot2_(Wq[3][rb].z, hq.z, a3); a3 = fdot2_(Wq[3][rb].w, hq.w, a3);
        }
        const float V = xpose4(a0, a1, a2, a3, q);
        const float a = V + fmaf(xS[t], wxv, biasx);
        const float act = fmaf(Ag, rcp_(1.f + ex2(a)), Cg);
        const float gi = dpp_mov(act, 0x00);
        const float gf = dpp_mov(act, 0x55);
        const float gg = dpp_mov(act, 0xAA);
        const float go = dpp_mov(act, 0xFF);
        c1 = fmaf(gf, c1, gi * gg);
        const float h = go * fmaf(-2.f, rcp_(1.f + ex2(K2L2E * c1)), 1.f);
        if (q == 0) {
            const u16 hb = __builtin_bit_cast(u16, (f16)h);
            ((u16*)hS[(t + 1) & 1])[2 * hswz(u >> 1) + (u & 1)] = hb;
            hO[t & 31][u] = hb;
        }
        __syncthreads();
        if ((t & 31) == 31) {   // coalesced chunk dump of h0 (f16 hi parts)
            *(u32x4*)((u16*)og + (size_t)(t - 31) * HH + tid * 8) =
                *(const u32x4*)(&hO[0][0] + tid * 8);
            __syncthreads();
        }
    }
}

// ============================ layer 1 + FC ==================================
// Exact R11 core; ONLY change: FC is software-pipelined by one step. Step i
// computes step i-1's FC chain from register hPrev at the TOP of the step,
// where it is independent of the dot chain and hides under the h ds_read
// latency. Step 31's FC runs post-loop (+1 barrier/chunk). Chain + fcP layout
// + gather are R11-verbatim.
__global__ __launch_bounds__(512, 2) void lstm1(
    const f16* __restrict__ h0g, const f16* __restrict__ Wpk1,
    const f16* __restrict__ W1h, const f16* __restrict__ W1l,
    const float* __restrict__ b1p, const float* __restrict__ fcw,
    const float* __restrict__ fcb, float* __restrict__ out)
{
    const int b = blockIdx.x;
    const int tid = threadIdx.x;
    const int u = tid >> 2, q = tid & 3;
    const int wv = tid >> 6, lane = tid & 63;
    const int lr = lane & 15, lq = lane >> 4;
    const bool is_g = (q == 2);
    const float Ag = is_g ? -2.f : 1.f;
    const float Cg = is_g ?  1.f : 0.f;

    __shared__ __align__(16) float xgS[32 * 512];   // 64 KB (row-XOR swizzled)
    __shared__ __align__(16) u32 hS1[2][64];        // packed f16 h, swizzled
    __shared__ __align__(16) float fcP[32][16];     // 2 KB step partials

    if (tid < 128) ((u32*)hS1)[tid] = 0u;
    const float fcu025 = fcw[u] * 0.25f;            // quad-redundancy factor
    const float fcbv = fcb[0];
    float c1 = 0.f;
    __syncthreads();

    const f16* hb0 = h0g + (size_t)b * TT * HH;
    float* ob = out + (size_t)b * TT;

#pragma unroll 1
    for (int t0 = 0; t0 < TT; t0 += 32) {
        // ---- proj: xgS = W_ih1(permuted,split) @ h0^T + bias (R9-verified) ----
        {
            f16x8 B0[4], B1[4];
#pragma unroll
            for (int ks = 0; ks < 4; ++ks) {
                B0[ks] = *(const f16x8*)(hb0 + (size_t)(t0 + lr) * HH + ks * 32 + lq * 8);
                B1[ks] = *(const f16x8*)(hb0 + (size_t)(t0 + 16 + lr) * HH + ks * 32 + lq * 8);
            }
#pragma unroll
            for (int gtl = 0; gtl < 4; ++gtl) {
                const int g16 = (wv * 4 + gtl) * 16;
                const float4 bi = *(const float4*)&b1p[g16 + lq * 4];
                f32x4 a0 = {bi.x, bi.y, bi.z, bi.w};
                f32x4 a1 = a0;
#pragma unroll
                for (int ks = 0; ks < 4; ++ks) {
                    const f16x8 Ah = *(const f16x8*)(W1h + (size_t)(g16 + lr) * HH + ks * 32 + lq * 8);
                    const f16x8 Al = *(const f16x8*)(W1l + (size_t)(g16 + lr) * HH + ks * 32 + lq * 8);
                    a0 = MFMA16(Ah, B0[ks], a0);
                    a0 = MFMA16(Al, B0[ks], a0);
                    a1 = MFMA16(Ah, B1[ks], a1);
                    a1 = MFMA16(Al, B1[ks], a1);
                }
                const int gb = g16 + lq * 4;
                *(f32x4*)&xgS[lr * 512 + (gb ^ ((lr & 7) << 2))] = a0;
                *(f32x4*)&xgS[(16 + lr) * 512 + (gb ^ ((lr & 7) << 2))] = a1;
            }
        }
        __syncthreads();

        // reload rec weights after proj (R9/R11 pattern)
        u32x4 Wq[4][4];
        {
            const u32* wb = (const u32*)Wpk1;
            asm volatile("" : "+v"(wb));
#pragma unroll
            for (int c = 0; c < 4; ++c) {
                const u32* wp = wb + (size_t)((tid & ~3) + c) * 64 + q * 16;
#pragma unroll
                for (int rb = 0; rb < 4; ++rb) Wq[c][rb] = *(const u32x4*)(wp + rb * 4);
            }
        }

        // ---- 32 recurrent steps; FC lagged by one step ----
        float hPrev = 0.f;
#pragma unroll 1
        for (int i = 0; i < 32; ++i) {
            const int t = t0 + i;
            const float xgv = xgS[i * 512 + (tid ^ ((i & 7) << 2))];

            // FC for step i-1 (independent of this step's dot chain)
            if (i > 0) {
                float pf = hPrev * fcu025;
                pf = dpp_add(pf, 0xB1);    // xor1
                pf = dpp_add(pf, 0x4E);    // xor2
                pf = dpp_add(pf, 0x141);   // xor4 (half-mirror, quads uniform)
                pf = dpp_add(pf, 0x140);   // xor8 (row mirror) -> 16-row sums
                pf += __int_as_float(__builtin_amdgcn_ds_swizzle(__float_as_int(pf), 0x401F)); // xor16
                if ((lane & 31) == 0) fcP[i - 1][wv * 2 + (lane >> 5)] = pf;
            }

            const u32* hcur = hS1[t & 1];
            float a0 = 0.f, a1 = 0.f, a2 = 0.f, a3 = 0.f;
#pragma unroll
            for (int rb = 0; rb < 4; ++rb) {
                const u32x4 hq = *(const u32x4*)(hcur + (q << 4) + (((rb + q) & 3) << 2));
                a0 = fdot2_(Wq[0][rb].x, hq.x, a0); a0 = fdot2_(Wq[0][rb].y, hq.y, a0);
                a0 = fdot2_(Wq[0][rb].z, hq.z, a0); a0 = fdot2_(Wq[0][rb].w, hq.w, a0);
                a1 = fdot2_(Wq[1][rb].x, hq.x, a1); a1 = fdot2_(Wq[1][rb].y, hq.y, a1);
                a1 = fdot2_(Wq[1][rb].z, hq.z, a1); a1 = fdot2_(Wq[1][rb].w, hq.w, a1);
                a2 = fdot2_(Wq[2][rb].x, hq.x, a2); a2 = fdot2_(Wq[2][rb].y, hq.y, a2);
                a2 = fdot2_(Wq[2][rb].z, hq.z, a2); a2 = fdot2_(Wq[2][rb].w, hq.w, a2);
                a3 = fdot2_(Wq[3][rb].x, hq.x, a3); a3 = fdot2_(Wq[3][rb].y, hq.y, a3);
                a3 = fdot2_(Wq[3][rb].z, hq.z, a3); a3 = fdot2_(Wq[3][rb].w, hq.w, a3);
            }
            const float V = xpose4(a0, a1, a2, a3, q);
            const float a = V + xgv;
            const float act = fmaf(Ag, rcp_(1.f + ex2(a)), Cg);
            const float gi = dpp_mov(act, 0x00);
            const float gf = dpp_mov(act, 0x55);
            const float gg = dpp_mov(act, 0xAA);
            const float go = dpp_mov(act, 0xFF);
            c1 = fmaf(gf, c1, gi * gg);
            const float h = go * fmaf(-2.f, rcp_(1.f + ex2(K2L2E * c1)), 1.f);
            if (q == 0)
                ((u16*)hS1[(t + 1) & 1])[2 * hswz(u >> 1) + (u & 1)] =
                    __builtin_bit_cast(u16, (f16)h);
            hPrev = h;
            __syncthreads();
        }

        // ---- FC for step 31 (post-loop), then gather ----
        {
            float pf = hPrev * fcu025;
            pf = dpp_add(pf, 0xB1);
            pf = dpp_add(pf, 0x4E);
            pf = dpp_add(pf, 0x141);
            pf = dpp_add(pf, 0x140);
            pf += __int_as_float(__builtin_amdgcn_ds_swizzle(__float_as_int(pf), 0x401F));
            if ((lane & 31) == 0) fcP[31][wv * 2 + (lane >> 5)] = pf;
        }
        __syncthreads();

        if (tid < 32) {
            float sacc = 0.f;
#pragma unroll
            for (int r = 0; r < 4; ++r) {
                const float4 v = *(const float4*)&fcP[tid][r * 4];
                sacc += (v.x + v.y) + (v.z + v.w);
            }
            ob[t0 + tid] = sacc + fcbv;
        }
        // gather threads pass the next proj's __syncthreads before any thread
        // can rewrite fcP (first rewrite is at step i=1, two barriers later)
    }
}

extern "C" void kernel_launch(void* const* d_in, const int* in_sizes, int n_in,
                              void* d_out, int out_size, void* d_ws, size_t ws_size,
                              hipStream_t stream)
{
    const float* x    = (const float*)d_in[0];
    const float* Wih0 = (const float*)d_in[1];
    const float* Whh0 = (const float*)d_in[2];
    const float* bih0 = (const float*)d_in[3];
    const float* bhh0 = (const float*)d_in[4];
    const float* Wih1 = (const float*)d_in[5];
    const float* Whh1 = (const float*)d_in[6];
    const float* bih1 = (const float*)d_in[7];
    const float* bhh1 = (const float*)d_in[8];
    const float* fcw  = (const float*)d_in[9];
    const float* fcb  = (const float*)d_in[10];
    float* out = (float*)d_out;

    f16* h0g  = (f16*)d_ws;                          // 256*1024*128 f16 = 64 MiB
    f16* Wpk0 = h0g + (size_t)256 * TT * HH;         // 128 KiB each
    f16* Wpk1 = Wpk0 + 512 * HH;
    f16* W1h  = Wpk1 + 512 * HH;
    f16* W1l  = W1h + 512 * HH;
    float* bx0 = (float*)(W1l + 512 * HH);
    float* wx0 = bx0 + 512;
    float* b1p = wx0 + 512;

    prep <<<512, 128, 0, stream>>>(Whh0, Whh1, Wih1, Wih0, bih0, bhh0, bih1, bhh1,
                                   Wpk0, Wpk1, W1h, W1l, bx0, wx0, b1p);
    lstm0<<<256, 512, 0, stream>>>(x, Wpk0, bx0, wx0, h0g);
    lstm1<<<256, 512, 0, stream>>>(h0g, Wpk1, W1h, W1l, b1p, fcw, fcb, out);
}

// Round 18
// 1264.735 us; speedup vs baseline: 1.1327x; 1.0278x over previous
//
#include <hip/hip_runtime.h>

#define TT 1024
#define HH 128

typedef unsigned int u32;
typedef unsigned short u16;
typedef _Float16 f16;
typedef f16 f16x2 __attribute__((ext_vector_type(2)));
typedef f16 f16x8 __attribute__((ext_vector_type(8)));
typedef float f32x4 __attribute__((ext_vector_type(4)));
typedef u32 u32x4 __attribute__((ext_vector_type(4)));

#define MFMA16(A, B, C) __builtin_amdgcn_mfma_f32_16x16x32_f16((A), (B), (C), 0, 0, 0)
#define K2L2E 2.8853900817779268f   /* 2*log2(e) */

__device__ __forceinline__ float ex2(float x) {
#if __has_builtin(__builtin_amdgcn_exp2f)
    return __builtin_amdgcn_exp2f(x);
#else
    extern "C" __device__ float __ocml_exp2_f32(float);
    return __ocml_exp2_f32(x);
#endif
}
__device__ __forceinline__ float rcp_(float x) { return __builtin_amdgcn_rcpf(x); }

__device__ __forceinline__ float fdot2_(u32 w, u32 h, float acc) {
#if __has_builtin(__builtin_amdgcn_fdot2)
    return __builtin_amdgcn_fdot2(__builtin_bit_cast(f16x2, w),
                                  __builtin_bit_cast(f16x2, h), acc, false);
#else
    const f16x2 a = __builtin_bit_cast(f16x2, w);
    const f16x2 b = __builtin_bit_cast(f16x2, h);
    return fmaf((float)a.y, (float)b.y, fmaf((float)a.x, (float)b.x, acc));
#endif
}

__device__ __forceinline__ float dpp_mov(float v, const int ctrl) {
    int t;
    switch (ctrl) {   // quad_perm patterns (R6-R11 verified)
      case 0x00: t = __builtin_amdgcn_update_dpp(0, __float_as_int(v), 0x00, 0xF, 0xF, true); break;
      case 0x55: t = __builtin_amdgcn_update_dpp(0, __float_as_int(v), 0x55, 0xF, 0xF, true); break;
      case 0xAA: t = __builtin_amdgcn_update_dpp(0, __float_as_int(v), 0xAA, 0xF, 0xF, true); break;
      case 0xFF: t = __builtin_amdgcn_update_dpp(0, __float_as_int(v), 0xFF, 0xF, 0xF, true); break;
      case 0xB1: t = __builtin_amdgcn_update_dpp(0, __float_as_int(v), 0xB1, 0xF, 0xF, true); break;
      default:   t = __builtin_amdgcn_update_dpp(0, __float_as_int(v), 0x4E, 0xF, 0xF, true); break;
    }
    return __int_as_float(t);
}
__device__ __forceinline__ float dpp_add(float v, const int ctrl) {
    int t;
    switch (ctrl) {
      case 0xB1:  t = __builtin_amdgcn_update_dpp(0, __float_as_int(v), 0xB1,  0xF, 0xF, true); break;
      case 0x4E:  t = __builtin_amdgcn_update_dpp(0, __float_as_int(v), 0x4E,  0xF, 0xF, true); break;
      case 0x141: t = __builtin_amdgcn_update_dpp(0, __float_as_int(v), 0x141, 0xF, 0xF, true); break;
      default:    t = __builtin_amdgcn_update_dpp(0, __float_as_int(v), 0x140, 0xF, 0xF, true); break;
    }
    return v + __int_as_float(t);
}

// swizzled LDS u32 index for the 512-thread h layout (block-rotation, R11)
__device__ __forceinline__ int hswz(int iu) {
    return (iu & 0x30) + (((((iu >> 2) & 3) + (iu >> 4)) & 3) << 2) + (iu & 3);
}

// 4x4 transpose-reduce within a quad (R11-verified)
__device__ __forceinline__ float xpose4(float a0, float a1, float a2, float a3, int q) {
    const bool qb0 = (q & 1) != 0;
    float s0, s1;
    {
        const float send = qb0 ? a0 : a1;
        s0 = (qb0 ? a1 : a0) + dpp_mov(send, 0xB1);
    }
    {
        const float send = qb0 ? a2 : a3;
        s1 = (qb0 ? a3 : a2) + dpp_mov(send, 0xB1);
    }
    const bool qb1 = (q & 2) != 0;
    const float send = qb1 ? s0 : s1;
    return (qb1 ? s1 : s0) + dpp_mov(send, 0x4E);
}

// ---------------- prep (identical to R9/R11-verified) -----------------------
__global__ void prep(const float* __restrict__ Whh0, const float* __restrict__ Whh1,
                     const float* __restrict__ Wih1, const float* __restrict__ Wih0,
                     const float* __restrict__ bih0, const float* __restrict__ bhh0,
                     const float* __restrict__ bih1, const float* __restrict__ bhh1,
                     f16* __restrict__ Wpk0, f16* __restrict__ Wpk1,
                     f16* __restrict__ W1h,  f16* __restrict__ W1l,
                     float* __restrict__ bx0, float* __restrict__ wx0,
                     float* __restrict__ b1p)
{
    const int p = blockIdx.x;       // 0..511
    const int k = threadIdx.x;      // 0..127
    const int c = p & 3, u = p >> 2;
    const int g = c * 128 + u;
    const float sc = (c == 2) ? K2L2E : -1.4426950408889634f;

    Wpk0[p * HH + k] = (f16)(Whh0[(size_t)g * HH + k] * sc);
    Wpk1[p * HH + k] = (f16)(Whh1[(size_t)g * HH + k] * sc);
    const float wf = Wih1[(size_t)g * HH + k] * sc;
    const f16 wh = (f16)wf;
    W1h[p * HH + k] = wh;
    W1l[p * HH + k] = (f16)(wf - (float)wh);
    if (k == 0) {
        bx0[p] = (bih0[g] + bhh0[g]) * sc;
        wx0[p] = Wih0[g] * sc;
        b1p[p] = (bih1[g] + bhh1[g]) * sc;
    }
}

// ============================ layer 0 =======================================
// 256 blocks (1 batch row), 512 threads. Thread = (unit u=tid>>2, quad slot
// q=tid&3): ALL 4 gates of u over K-quarter q -> 64 packed weight u32 in VGPRs,
// only 4 ds_read_b128 of h per step. DPP transpose-reduce -> lane q holds gate
// q; quad broadcasts unchanged. h LDS block-rotated (bank-conflict-free).
__global__ __launch_bounds__(512, 2) void lstm0(
    const float* __restrict__ x, const f16* __restrict__ Wpk0,
    const float* __restrict__ bx0, const float* __restrict__ wx0,
    f16* __restrict__ h0g)
{
    const int b = blockIdx.x;
    const int tid = threadIdx.x;
    const int u = tid >> 2, q = tid & 3;
    const bool is_g = (q == 2);
    const float Ag = is_g ? -2.f : 1.f;
    const float Cg = is_g ?  1.f : 0.f;

    __shared__ __align__(16) float xS[TT];          // 4 KB
    __shared__ __align__(16) u32 hS[2][64];         // packed f16 h, swizzled
    __shared__ __align__(16) u16 hO[32][HH];        // 8 KB chunk staging

    xS[tid]       = x[(size_t)b * TT + tid];
    xS[tid + 512] = x[(size_t)b * TT + tid + 512];
    if (tid < 128) ((u32*)hS)[tid] = 0u;

    u32x4 Wq[4][4];
#pragma unroll
    for (int c = 0; c < 4; ++c) {
        const u32* wp = (const u32*)Wpk0 + (size_t)((tid & ~3) + c) * 64 + q * 16;
#pragma unroll
        for (int rb = 0; rb < 4; ++rb) Wq[c][rb] = *(const u32x4*)(wp + rb * 4);
    }
    const float biasx = bx0[tid];
    const float wxv   = wx0[tid];
    float c1 = 0.f;
    __syncthreads();

    f16* og = h0g + (size_t)b * TT * HH;

#pragma unroll 1
    for (int t = 0; t < TT; ++t) {
        const u32* hcur = hS[t & 1];
        float a0 = 0.f, a1 = 0.f, a2 = 0.f, a3 = 0.f;
#pragma unroll
        for (int rb = 0; rb < 4; ++rb) {
            const u32x4 hq = *(const u32x4*)(hcur + (q << 4) + (((rb + q) & 3) << 2));
            a0 = fdot2_(Wq[0][rb].x, hq.x, a0); a0 = fdot2_(Wq[0][rb].y, hq.y, a0);
            a0 = fdot2_(Wq[0][rb].z, hq.z, a0); a0 = fdot2_(Wq[0][rb].w, hq.w, a0);
            a1 = fdot2_(Wq[1][rb].x, hq.x, a1); a1 = fdot2_(Wq[1][rb].y, hq.y, a1);
            a1 = fdot2_(Wq[1][rb].z, hq.z, a1); a1 = fdot2_(Wq[1][rb].w, hq.w, a1);
            a2 = fdot2_(Wq[2][rb].x, hq.x, a2); a2 = fdot2_(Wq[2][rb].y, hq.y, a2);
            a2 = fdot2_(Wq[2][rb].z, hq.z, a2); a2 = fdot2_(Wq[2][rb].w, hq.w, a2);
            a3 = fdot2_(Wq[3][rb].x, hq.x, a3); a3 = fdot2_(Wq[3][rb].y, hq.y, a3);
            a3 = fdot2_(Wq[3][rb].z, hq.z, a3); a3 = fdot2_(Wq[3][rb].w, hq.w, a3);
        }
        const float V = xpose4(a0, a1, a2, a3, q);
        const float a = V + fmaf(xS[t], wxv, biasx);
        const float act = fmaf(Ag, rcp_(1.f + ex2(a)), Cg);
        const float gi = dpp_mov(act, 0x00);
        const float gf = dpp_mov(act, 0x55);
        const float gg = dpp_mov(act, 0xAA);
        const float go = dpp_mov(act, 0xFF);
        c1 = fmaf(gf, c1, gi * gg);
        const float h = go * fmaf(-2.f, rcp_(1.f + ex2(K2L2E * c1)), 1.f);
        if (q == 0) {
            const u16 hb = __builtin_bit_cast(u16, (f16)h);
            ((u16*)hS[(t + 1) & 1])[2 * hswz(u >> 1) + (u & 1)] = hb;
            hO[t & 31][u] = hb;
        }
        __syncthreads();
        if ((t & 31) == 31) {   // coalesced chunk dump of h0 (f16 hi parts)
            *(u32x4*)((u16*)og + (size_t)(t - 31) * HH + tid * 8) =
                *(const u32x4*)(&hO[0][0] + tid * 8);
            __syncthreads();
        }
    }
}

// ============================ layer 1 + FC ==================================
// R11-verified: K-quarter rec core; per chunk MFMA input proj -> xgS; per-step
// FC = 4 DPP row-adds + 1 xor16 swizzle, 2 partials/wave/step; cross-wave
// gather once per chunk.
__global__ __launch_bounds__(512, 2) void lstm1(
    const f16* __restrict__ h0g, const f16* __restrict__ Wpk1,
    const f16* __restrict__ W1h, const f16* __restrict__ W1l,
    const float* __restrict__ b1p, const float* __restrict__ fcw,
    const float* __restrict__ fcb, float* __restrict__ out)
{
    const int b = blockIdx.x;
    const int tid = threadIdx.x;
    const int u = tid >> 2, q = tid & 3;
    const int wv = tid >> 6, lane = tid & 63;
    const int lr = lane & 15, lq = lane >> 4;
    const bool is_g = (q == 2);
    const float Ag = is_g ? -2.f : 1.f;
    const float Cg = is_g ?  1.f : 0.f;

    __shared__ __align__(16) float xgS[32 * 512];   // 64 KB (row-XOR swizzled)
    __shared__ __align__(16) u32 hS1[2][64];        // packed f16 h, swizzled
    __shared__ __align__(16) float fcP[32][16];     // 2 KB step partials

    if (tid < 128) ((u32*)hS1)[tid] = 0u;
    const float fcu025 = fcw[u] * 0.25f;            // quad-redundancy factor
    const float fcbv = fcb[0];
    float c1 = 0.f;
    __syncthreads();

    const f16* hb0 = h0g + (size_t)b * TT * HH;
    float* ob = out + (size_t)b * TT;

#pragma unroll 1
    for (int t0 = 0; t0 < TT; t0 += 32) {
        // ---- proj: xgS = W_ih1(permuted,split) @ h0^T + bias (R9-verified) ----
        {
            f16x8 B0[4], B1[4];
#pragma unroll
            for (int ks = 0; ks < 4; ++ks) {
                B0[ks] = *(const f16x8*)(hb0 + (size_t)(t0 + lr) * HH + ks * 32 + lq * 8);
                B1[ks] = *(const f16x8*)(hb0 + (size_t)(t0 + 16 + lr) * HH + ks * 32 + lq * 8);
            }
#pragma unroll
            for (int gtl = 0; gtl < 4; ++gtl) {
                const int g16 = (wv * 4 + gtl) * 16;
                const float4 bi = *(const float4*)&b1p[g16 + lq * 4];
                f32x4 a0 = {bi.x, bi.y, bi.z, bi.w};
                f32x4 a1 = a0;
#pragma unroll
                for (int ks = 0; ks < 4; ++ks) {
                    const f16x8 Ah = *(const f16x8*)(W1h + (size_t)(g16 + lr) * HH + ks * 32 + lq * 8);
                    const f16x8 Al = *(const f16x8*)(W1l + (size_t)(g16 + lr) * HH + ks * 32 + lq * 8);
                    a0 = MFMA16(Ah, B0[ks], a0);
                    a0 = MFMA16(Al, B0[ks], a0);
                    a1 = MFMA16(Ah, B1[ks], a1);
                    a1 = MFMA16(Al, B1[ks], a1);
                }
                const int gb = g16 + lq * 4;
                *(f32x4*)&xgS[lr * 512 + (gb ^ ((lr & 7) << 2))] = a0;
                *(f32x4*)&xgS[(16 + lr) * 512 + (gb ^ ((lr & 7) << 2))] = a1;
            }
        }
        __syncthreads();

        // reload rec weights after proj (R9/R11 pattern)
        u32x4 Wq[4][4];
        {
            const u32* wb = (const u32*)Wpk1;
            asm volatile("" : "+v"(wb));
#pragma unroll
            for (int c = 0; c < 4; ++c) {
                const u32* wp = wb + (size_t)((tid & ~3) + c) * 64 + q * 16;
#pragma unroll
                for (int rb = 0; rb < 4; ++rb) Wq[c][rb] = *(const u32x4*)(wp + rb * 4);
            }
        }

        // ---- 32 recurrent steps ----
#pragma unroll 1
        for (int i = 0; i < 32; ++i) {
            const int t = t0 + i;
            const float xgv = xgS[i * 512 + (tid ^ ((i & 7) << 2))];
            const u32* hcur = hS1[t & 1];
            float a0 = 0.f, a1 = 0.f, a2 = 0.f, a3 = 0.f;
#pragma unroll
            for (int rb = 0; rb < 4; ++rb) {
                const u32x4 hq = *(const u32x4*)(hcur + (q << 4) + (((rb + q) & 3) << 2));
                a0 = fdot2_(Wq[0][rb].x, hq.x, a0); a0 = fdot2_(Wq[0][rb].y, hq.y, a0);
                a0 = fdot2_(Wq[0][rb].z, hq.z, a0); a0 = fdot2_(Wq[0][rb].w, hq.w, a0);
                a1 = fdot2_(Wq[1][rb].x, hq.x, a1); a1 = fdot2_(Wq[1][rb].y, hq.y, a1);
                a1 = fdot2_(Wq[1][rb].z, hq.z, a1); a1 = fdot2_(Wq[1][rb].w, hq.w, a1);
                a2 = fdot2_(Wq[2][rb].x, hq.x, a2); a2 = fdot2_(Wq[2][rb].y, hq.y, a2);
                a2 = fdot2_(Wq[2][rb].z, hq.z, a2); a2 = fdot2_(Wq[2][rb].w, hq.w, a2);
                a3 = fdot2_(Wq[3][rb].x, hq.x, a3); a3 = fdot2_(Wq[3][rb].y, hq.y, a3);
                a3 = fdot2_(Wq[3][rb].z, hq.z, a3); a3 = fdot2_(Wq[3][rb].w, hq.w, a3);
            }
            const float V = xpose4(a0, a1, a2, a3, q);
            const float a = V + xgv;
            const float act = fmaf(Ag, rcp_(1.f + ex2(a)), Cg);
            const float gi = dpp_mov(act, 0x00);
            const float gf = dpp_mov(act, 0x55);
            const float gg = dpp_mov(act, 0xAA);
            const float go = dpp_mov(act, 0xFF);
            c1 = fmaf(gf, c1, gi * gg);
            const float h = go * fmaf(-2.f, rcp_(1.f + ex2(K2L2E * c1)), 1.f);
            if (q == 0)
                ((u16*)hS1[(t + 1) & 1])[2 * hswz(u >> 1) + (u & 1)] =
                    __builtin_bit_cast(u16, (f16)h);

            // FC partial: quad-redundant h, wave-local reduce
            float pf = h * fcu025;
            pf = dpp_add(pf, 0xB1);    // xor1
            pf = dpp_add(pf, 0x4E);    // xor2
            pf = dpp_add(pf, 0x141);   // xor4 (half-mirror, quads uniform)
            pf = dpp_add(pf, 0x140);   // xor8 (row mirror) -> 16-row sums
            pf += __int_as_float(__builtin_amdgcn_ds_swizzle(__float_as_int(pf), 0x401F)); // xor16
            if ((lane & 31) == 0) fcP[i][wv * 2 + (lane >> 5)] = pf;
            __syncthreads();
        }

        // ---- chunk-end FC gather: 32 outputs ----
        if (tid < 32) {
            float s = 0.f;
#pragma unroll
            for (int r = 0; r < 4; ++r) {
                const float4 v = *(const float4*)&fcP[tid][r * 4];
                s += (v.x + v.y) + (v.z + v.w);
            }
            ob[t0 + tid] = s + fcbv;
        }
        // ordering: gather threads pass the next proj's __syncthreads before
        // any thread can write fcP again -> no extra barrier needed
    }
}

extern "C" void kernel_launch(void* const* d_in, const int* in_sizes, int n_in,
                              void* d_out, int out_size, void* d_ws, size_t ws_size,
                              hipStream_t stream)
{
    const float* x    = (const float*)d_in[0];
    const float* Wih0 = (const float*)d_in[1];
    const float* Whh0 = (const float*)d_in[2];
    const float* bih0 = (const float*)d_in[3];
    const float* bhh0 = (const float*)d_in[4];
    const float* Wih1 = (const float*)d_in[5];
    const float* Whh1 = (const float*)d_in[6];
    const float* bih1 = (const float*)d_in[7];
    const float* bhh1 = (const float*)d_in[8];
    const float* fcw  = (const float*)d_in[9];
    const float* fcb  = (const float*)d_in[10];
    float* out = (float*)d_out;

    f16* h0g  = (f16*)d_ws;                          // 256*1024*128 f16 = 64 MiB
    f16* Wpk0 = h0g + (size_t)256 * TT * HH;         // 128 KiB each
    f16* Wpk1 = Wpk0 + 512 * HH;
    f16* W1h  = Wpk1 + 512 * HH;
    f16* W1l  = W1h + 512 * HH;
    float* bx0 = (float*)(W1l + 512 * HH);
    float* wx0 = bx0 + 512;
    float* b1p = wx0 + 512;

    prep <<<512, 128, 0, stream>>>(Whh0, Whh1, Wih1, Wih0, bih0, bhh0, bih1, bhh1,
                                   Wpk0, Wpk1, W1h, W1l, bx0, wx0, b1p);
    lstm0<<<256, 512, 0, stream>>>(x, Wpk0, bx0, wx0, h0g);
    lstm1<<<256, 512, 0, stream>>>(h0g, Wpk1, W1h, W1l, b1p, fcw, fcb, out);
}